// Round 1
// baseline (1364.684 us; speedup 1.0000x reference)
//
#include <hip/hip_runtime.h>

typedef __bf16 bf16_t;
typedef __bf16 bf16x8 __attribute__((ext_vector_type(8)));
typedef __bf16 bf16x4 __attribute__((ext_vector_type(4)));
typedef float f32x4 __attribute__((ext_vector_type(4)));

#define NTOK 1568
#define CDIM 512
#define BATCH 4
#define MROWS (BATCH*NTOK)  // 6272
#define RSQ1PEPS 0.9999950000374997f

// ---------------- cast f32 -> bf16 (weights) ----------------
__global__ __launch_bounds__(256) void cast_kernel(const float* __restrict__ in,
                                                   bf16_t* __restrict__ out) {
  int i = blockIdx.x * 256 + threadIdx.x;     // one float4 per thread
  float4 v = ((const float4*)in)[i];
  bf16x4 o;
  o[0] = (bf16_t)v.x; o[1] = (bf16_t)v.y; o[2] = (bf16_t)v.z; o[3] = (bf16_t)v.w;
  *(bf16x4*)(out + (size_t)i * 4) = o;
}

// ---------------- tokenize: x[b][c][s] -> t[b][s][c] (f32 + bf16) ----------------
__global__ __launch_bounds__(256) void tok_kernel(const float* __restrict__ x,
                                                  float* __restrict__ tf,
                                                  bf16_t* __restrict__ tb) {
  __shared__ float tile[32][33];
  int b = blockIdx.z;
  int c0 = blockIdx.y * 32, s0 = blockIdx.x * 32;
  int tx = threadIdx.x, ty = threadIdx.y;   // (32, 8)
  const float* xp = x + (size_t)b * CDIM * NTOK;
  for (int r = 0; r < 32; r += 8)
    tile[ty + r][tx] = xp[(size_t)(c0 + ty + r) * NTOK + s0 + tx];
  __syncthreads();
  float* tfp = tf + (size_t)b * NTOK * CDIM;
  bf16_t* tbp = tb + (size_t)b * NTOK * CDIM;
  for (int r = 0; r < 32; r += 8) {
    float v = tile[tx][ty + r];
    size_t idx = (size_t)(s0 + ty + r) * CDIM + c0 + tx;
    tfp[idx] = v;
    tbp[idx] = (bf16_t)v;
  }
}

// ---------------- LayerNorm: f32 in -> bf16 out ----------------
__global__ __launch_bounds__(64) void ln_kernel(const float* __restrict__ t,
                                                const float* __restrict__ g,
                                                const float* __restrict__ bt,
                                                bf16_t* __restrict__ out) {
  int row = blockIdx.x;
  int l = threadIdx.x;  // 64
  const float* x = t + (size_t)row * CDIM;
  float4 v0 = ((const float4*)x)[l];
  float4 v1 = ((const float4*)x)[l + 64];
  float s = v0.x + v0.y + v0.z + v0.w + v1.x + v1.y + v1.z + v1.w;
  float sq = v0.x*v0.x + v0.y*v0.y + v0.z*v0.z + v0.w*v0.w
           + v1.x*v1.x + v1.y*v1.y + v1.z*v1.z + v1.w*v1.w;
  for (int m = 1; m < 64; m <<= 1) { s += __shfl_xor(s, m); sq += __shfl_xor(sq, m); }
  float mean = s * (1.f / 512.f);
  float var = sq * (1.f / 512.f) - mean * mean;
  float rs = rsqrtf(var + 1e-5f);
  float4 g0 = ((const float4*)g)[l], g1 = ((const float4*)g)[l + 64];
  float4 b0 = ((const float4*)bt)[l], b1 = ((const float4*)bt)[l + 64];
  bf16x4 o0, o1;
  o0[0] = (bf16_t)((v0.x - mean) * rs * g0.x + b0.x);
  o0[1] = (bf16_t)((v0.y - mean) * rs * g0.y + b0.y);
  o0[2] = (bf16_t)((v0.z - mean) * rs * g0.z + b0.z);
  o0[3] = (bf16_t)((v0.w - mean) * rs * g0.w + b0.w);
  o1[0] = (bf16_t)((v1.x - mean) * rs * g1.x + b1.x);
  o1[1] = (bf16_t)((v1.y - mean) * rs * g1.y + b1.y);
  o1[2] = (bf16_t)((v1.z - mean) * rs * g1.z + b1.z);
  o1[3] = (bf16_t)((v1.w - mean) * rs * g1.w + b1.w);
  *(bf16x4*)(out + (size_t)row * CDIM + l * 4) = o0;
  *(bf16x4*)(out + (size_t)row * CDIM + 256 + l * 4) = o1;
}

// ---------------- GEMM: D[M][N] = A[M][512] * B[N][512]^T ----------------
// MODE 0: proj -> bf16 out [M][512], bias per col.
// MODE 1: out-head (A=W[512][512], B=tokens per batch) -> f32 out [b][512][1568],
//         bias/bn per row(=channel), relu+bn epilogue, col mask (N=1568).
template<int MODE>
__global__ __launch_bounds__(256) void gemm_kernel(
    const bf16_t* __restrict__ A, const bf16_t* __restrict__ B,
    const float* __restrict__ bias, const float* __restrict__ bng,
    const float* __restrict__ bnb, bf16_t* __restrict__ outb,
    float* __restrict__ outf, int Nvalid) {
  int z = blockIdx.z;
  const bf16_t* Bp = B;
  float* outfp = outf;
  if (MODE == 1) {
    Bp += (size_t)z * NTOK * CDIM;
    outfp += (size_t)z * CDIM * NTOK;
  }
  int m0 = blockIdx.y * 128, n0 = blockIdx.x * 128;
  __shared__ bf16_t As[128][40];
  __shared__ bf16_t Bs[128][40];
  int tid = threadIdx.x;
  int w = tid >> 6, l = tid & 63, lr = l & 15, kg = l >> 4;
  int wm = (w >> 1) * 64, wn = (w & 1) * 64;
  f32x4 acc[4][4];
  for (int i = 0; i < 4; i++)
    for (int j = 0; j < 4; j++)
      acc[i][j] = f32x4{0.f, 0.f, 0.f, 0.f};
  int srow = tid >> 1;
  int soff = (tid & 1) * 16;
  int brow = n0 + srow;
  if (MODE == 1 && brow >= Nvalid) brow = Nvalid - 1;
  const bf16_t* aq = A + (size_t)(m0 + srow) * CDIM + soff;
  const bf16_t* bq = Bp + (size_t)brow * CDIM + soff;
  for (int kk = 0; kk < 16; kk++) {
    __syncthreads();
    bf16x8 a0 = *(const bf16x8*)(aq);
    bf16x8 a1 = *(const bf16x8*)(aq + 8);
    bf16x8 b0 = *(const bf16x8*)(bq);
    bf16x8 b1 = *(const bf16x8*)(bq + 8);
    aq += 32; bq += 32;
    *(bf16x8*)&As[srow][soff] = a0;
    *(bf16x8*)&As[srow][soff + 8] = a1;
    *(bf16x8*)&Bs[srow][soff] = b0;
    *(bf16x8*)&Bs[srow][soff + 8] = b1;
    __syncthreads();
    bf16x8 af[4], bfr[4];
    for (int i = 0; i < 4; i++) af[i] = *(const bf16x8*)&As[wm + i * 16 + lr][kg * 8];
    for (int j = 0; j < 4; j++) bfr[j] = *(const bf16x8*)&Bs[wn + j * 16 + lr][kg * 8];
    for (int i = 0; i < 4; i++)
      for (int j = 0; j < 4; j++)
        acc[i][j] = __builtin_amdgcn_mfma_f32_16x16x32_bf16(af[i], bfr[j], acc[i][j], 0, 0, 0);
  }
  for (int i = 0; i < 4; i++)
    for (int j = 0; j < 4; j++) {
      int rbase = m0 + wm + i * 16 + kg * 4;
      int col = n0 + wn + j * 16 + lr;
      for (int r = 0; r < 4; r++) {
        int row = rbase + r;
        float v = acc[i][j][r];
        if (MODE == 0) {
          v += bias[col];
          outb[(size_t)row * CDIM + col] = (bf16_t)v;
        } else {
          v += bias[row];
          v = v > 0.f ? v : 0.f;
          v *= RSQ1PEPS;
          v = v * bng[row] + bnb[row];
          if (col < Nvalid) outfp[(size_t)row * NTOK + col] = v;
        }
      }
    }
}

// ---------------- flash attention (cross), one block = (qtile64, head, batch) ----------------
__global__ __launch_bounds__(256) void attn_kernel(
    const bf16_t* __restrict__ qb, const bf16_t* __restrict__ kb,
    const bf16_t* __restrict__ vb, float* __restrict__ tf, bf16_t* __restrict__ tb) {
  int b = blockIdx.z, h = blockIdx.y, qt = blockIdx.x;
  int tid = threadIdx.x, w = tid >> 6, l = tid & 63, lr = l & 15, kg = l >> 4;
  __shared__ bf16_t Ks[32][72];
  __shared__ bf16_t Vt[64][40];
  __shared__ bf16_t Ps[4][16][40];

  const size_t base = ((size_t)b * NTOK) * CDIM + h * 64;
  int qrow = qt * 64 + w * 16 + lr;
  int qrc = qrow < NTOK ? qrow : NTOK - 1;
  bf16x8 qf[2];
  qf[0] = *(const bf16x8*)(qb + base + (size_t)qrc * CDIM + kg * 8);
  qf[1] = *(const bf16x8*)(qb + base + (size_t)qrc * CDIM + 32 + kg * 8);

  float m_i[4], l_i[4];
  for (int i = 0; i < 4; i++) { m_i[i] = -1e30f; l_i[i] = 0.f; }
  f32x4 o[4];
  for (int n = 0; n < 4; n++) o[n] = f32x4{0.f, 0.f, 0.f, 0.f};

  for (int kt = 0; kt < 49; kt++) {
    __syncthreads();
    {
      int r = tid >> 3, c8 = (tid & 7) * 8;
      const bf16_t* kp = kb + base + (size_t)(kt * 32 + r) * CDIM + c8;
      *(bf16x8*)&Ks[r][c8] = *(const bf16x8*)kp;
      const bf16_t* vp = vb + base + (size_t)(kt * 32 + r) * CDIM + c8;
      bf16x8 vv = *(const bf16x8*)vp;
      for (int j = 0; j < 8; j++) Vt[c8 + j][r] = vv[j];
    }
    __syncthreads();
    // QK^T : S[16 q][32 k]
    f32x4 s[2];
    s[0] = f32x4{0.f, 0.f, 0.f, 0.f};
    s[1] = f32x4{0.f, 0.f, 0.f, 0.f};
    for (int n = 0; n < 2; n++)
      for (int c = 0; c < 2; c++) {
        bf16x8 bk = *(const bf16x8*)&Ks[n * 16 + lr][c * 32 + kg * 8];
        s[n] = __builtin_amdgcn_mfma_f32_16x16x32_bf16(qf[c], bk, s[n], 0, 0, 0);
      }
    // online softmax (rows = kg*4+i, replicated across 16 lanes)
    float alpha[4];
    for (int i = 0; i < 4; i++) {
      float a0 = s[0][i] * 0.125f, a1 = s[1][i] * 0.125f;
      s[0][i] = a0; s[1][i] = a1;
      float v = fmaxf(a0, a1);
      v = fmaxf(v, __shfl_xor(v, 1));
      v = fmaxf(v, __shfl_xor(v, 2));
      v = fmaxf(v, __shfl_xor(v, 4));
      v = fmaxf(v, __shfl_xor(v, 8));
      float mn = fmaxf(m_i[i], v);
      alpha[i] = __expf(m_i[i] - mn);
      m_i[i] = mn;
      float p0 = __expf(a0 - mn);
      float p1 = __expf(a1 - mn);
      s[0][i] = p0; s[1][i] = p1;
      float ps = p0 + p1;
      ps += __shfl_xor(ps, 1);
      ps += __shfl_xor(ps, 2);
      ps += __shfl_xor(ps, 4);
      ps += __shfl_xor(ps, 8);
      l_i[i] = l_i[i] * alpha[i] + ps;
    }
    for (int n = 0; n < 4; n++)
      for (int i = 0; i < 4; i++) o[n][i] *= alpha[i];
    // P -> LDS (C-layout -> A-layout bounce)
    for (int n = 0; n < 2; n++)
      for (int i = 0; i < 4; i++)
        Ps[w][kg * 4 + i][n * 16 + lr] = (bf16_t)s[n][i];
    __syncthreads();
    // PV : O[16 q][64 d] += P[16][32] * V[32][64]
    bf16x8 pa = *(const bf16x8*)&Ps[w][lr][kg * 8];
    for (int n = 0; n < 4; n++) {
      bf16x8 bv = *(const bf16x8*)&Vt[n * 16 + lr][kg * 8];
      o[n] = __builtin_amdgcn_mfma_f32_16x16x32_bf16(pa, bv, o[n], 0, 0, 0);
    }
  }
  // finalize: residual add, write f32 + bf16 mirrors
  int qbase_o = qt * 64 + w * 16 + kg * 4;
  for (int i = 0; i < 4; i++) {
    int qr = qbase_o + i;
    if (qr < NTOK) {
      float inv = 1.0f / l_i[i];
      for (int n = 0; n < 4; n++) {
        size_t idx = base + (size_t)qr * CDIM + n * 16 + lr;
        float v = tf[idx] + o[n][i] * inv;
        tf[idx] = v;
        tb[idx] = (bf16_t)v;
      }
    }
  }
}

extern "C" void kernel_launch(void* const* d_in, const int* in_sizes, int n_in,
                              void* d_out, int out_size, void* d_ws, size_t ws_size,
                              hipStream_t stream) {
  (void)in_sizes; (void)n_in; (void)out_size; (void)ws_size;
  const float* x1 = (const float*)d_in[0];
  const float* x2 = (const float*)d_in[1];
  const float* Wq1 = (const float*)d_in[2];
  const float* bq1 = (const float*)d_in[3];
  const float* Wk1 = (const float*)d_in[4];
  const float* bk1 = (const float*)d_in[5];
  const float* Wv1 = (const float*)d_in[6];
  const float* bv1 = (const float*)d_in[7];
  const float* ln1_g = (const float*)d_in[8];
  const float* ln1_b = (const float*)d_in[9];
  const float* Wq2 = (const float*)d_in[10];
  const float* bq2 = (const float*)d_in[11];
  const float* Wk2 = (const float*)d_in[12];
  const float* bk2 = (const float*)d_in[13];
  const float* Wv2 = (const float*)d_in[14];
  const float* bv2 = (const float*)d_in[15];
  const float* ln2_g = (const float*)d_in[16];
  const float* ln2_b = (const float*)d_in[17];
  const float* out1_w = (const float*)d_in[18];
  const float* out1_b = (const float*)d_in[19];
  const float* bn1_g = (const float*)d_in[20];
  const float* bn1_b = (const float*)d_in[21];
  const float* out2_w = (const float*)d_in[22];
  const float* out2_b = (const float*)d_in[23];
  const float* bn2_g = (const float*)d_in[24];
  const float* bn2_b = (const float*)d_in[25];

  const size_t WMAT = 512 * 512;            // elems per weight matrix
  char* ws = (char*)d_ws;
  bf16_t* wb = (bf16_t*)ws;                 // 20 matrices bf16
  size_t off = 20 * WMAT * sizeof(bf16_t);
  float* t1f = (float*)(ws + off); off += (size_t)MROWS * CDIM * 4;
  float* t2f = (float*)(ws + off); off += (size_t)MROWS * CDIM * 4;
  bf16_t* t1b = (bf16_t*)(ws + off); off += (size_t)MROWS * CDIM * 2;
  bf16_t* t2b = (bf16_t*)(ws + off); off += (size_t)MROWS * CDIM * 2;
  bf16_t* l1b = (bf16_t*)(ws + off); off += (size_t)MROWS * CDIM * 2;
  bf16_t* l2b = (bf16_t*)(ws + off); off += (size_t)MROWS * CDIM * 2;
  bf16_t* q1b = (bf16_t*)(ws + off); off += (size_t)MROWS * CDIM * 2;
  bf16_t* k1b = (bf16_t*)(ws + off); off += (size_t)MROWS * CDIM * 2;
  bf16_t* v1b = (bf16_t*)(ws + off); off += (size_t)MROWS * CDIM * 2;
  bf16_t* q2b = (bf16_t*)(ws + off); off += (size_t)MROWS * CDIM * 2;
  bf16_t* k2b = (bf16_t*)(ws + off); off += (size_t)MROWS * CDIM * 2;
  bf16_t* v2b = (bf16_t*)(ws + off); off += (size_t)MROWS * CDIM * 2;

  // cast weights to bf16: order Wq1(0-2) Wk1(3-5) Wv1(6-8) Wq2(9-11) Wk2(12-14) Wv2(15-17) out1(18) out2(19)
  cast_kernel<<<768, 256, 0, stream>>>(Wq1, wb + 0 * WMAT);
  cast_kernel<<<768, 256, 0, stream>>>(Wk1, wb + 3 * WMAT);
  cast_kernel<<<768, 256, 0, stream>>>(Wv1, wb + 6 * WMAT);
  cast_kernel<<<768, 256, 0, stream>>>(Wq2, wb + 9 * WMAT);
  cast_kernel<<<768, 256, 0, stream>>>(Wk2, wb + 12 * WMAT);
  cast_kernel<<<768, 256, 0, stream>>>(Wv2, wb + 15 * WMAT);
  cast_kernel<<<256, 256, 0, stream>>>(out1_w, wb + 18 * WMAT);
  cast_kernel<<<256, 256, 0, stream>>>(out2_w, wb + 19 * WMAT);

  // tokenize
  tok_kernel<<<dim3(49, 16, 4), dim3(32, 8), 0, stream>>>(x1, t1f, t1b);
  tok_kernel<<<dim3(49, 16, 4), dim3(32, 8), 0, stream>>>(x2, t2f, t2b);

  dim3 gp(4, 49, 1);
  dim3 ga(25, 8, 4);
  for (int i = 0; i < 3; i++) {
    ln_kernel<<<6272, 64, 0, stream>>>(t1f, ln1_g + i * 512, ln1_b + i * 512, l1b);
    ln_kernel<<<6272, 64, 0, stream>>>(t2f, ln2_g + i * 512, ln2_b + i * 512, l2b);
    gemm_kernel<0><<<gp, 256, 0, stream>>>(l1b, wb + (0 + i) * WMAT, bq1 + i * 512,
                                           nullptr, nullptr, q1b, nullptr, 512);
    gemm_kernel<0><<<gp, 256, 0, stream>>>(t2b, wb + (3 + i) * WMAT, bk1 + i * 512,
                                           nullptr, nullptr, k1b, nullptr, 512);
    gemm_kernel<0><<<gp, 256, 0, stream>>>(t2b, wb + (6 + i) * WMAT, bv1 + i * 512,
                                           nullptr, nullptr, v1b, nullptr, 512);
    gemm_kernel<0><<<gp, 256, 0, stream>>>(l2b, wb + (9 + i) * WMAT, bq2 + i * 512,
                                           nullptr, nullptr, q2b, nullptr, 512);
    gemm_kernel<0><<<gp, 256, 0, stream>>>(t1b, wb + (12 + i) * WMAT, bk2 + i * 512,
                                           nullptr, nullptr, k2b, nullptr, 512);
    gemm_kernel<0><<<gp, 256, 0, stream>>>(t1b, wb + (15 + i) * WMAT, bv2 + i * 512,
                                           nullptr, nullptr, v2b, nullptr, 512);
    attn_kernel<<<ga, 256, 0, stream>>>(q1b, k1b, v1b, t1f, t1b);
    attn_kernel<<<ga, 256, 0, stream>>>(q2b, k2b, v2b, t2f, t2b);
  }

  // out heads (transposed GEMM: rows=channels, cols=tokens -> coalesced permuted store)
  float* out = (float*)d_out;
  dim3 gh(13, 4, 4);
  gemm_kernel<1><<<gh, 256, 0, stream>>>(wb + 18 * WMAT, t1b, out1_b, bn1_g, bn1_b,
                                         nullptr, out, NTOK);
  gemm_kernel<1><<<gh, 256, 0, stream>>>(wb + 19 * WMAT, t2b, out2_b, bn2_g, bn2_b,
                                         nullptr, out + (size_t)BATCH * CDIM * NTOK, NTOK);
}

// Round 2
// 838.657 us; speedup vs baseline: 1.6272x; 1.6272x over previous
//
#include <hip/hip_runtime.h>

typedef __bf16 bf16_t;
typedef __bf16 bf16x8 __attribute__((ext_vector_type(8)));
typedef __bf16 bf16x4 __attribute__((ext_vector_type(4)));
typedef float f32x4 __attribute__((ext_vector_type(4)));
typedef float f32x16 __attribute__((ext_vector_type(16)));
typedef unsigned u32x4 __attribute__((ext_vector_type(4)));

#define NTOK 1568
#define CDIM 512
#define BATCH 4
#define MROWS (BATCH*NTOK)  // 6272
#define RSQ1PEPS 0.9999950000374997f

// ---------------- cast f32 -> bf16 (weights) ----------------
__global__ __launch_bounds__(256) void cast_kernel(const float* __restrict__ in,
                                                   bf16_t* __restrict__ out) {
  int i = blockIdx.x * 256 + threadIdx.x;     // one float4 per thread
  float4 v = ((const float4*)in)[i];
  bf16x4 o;
  o[0] = (bf16_t)v.x; o[1] = (bf16_t)v.y; o[2] = (bf16_t)v.z; o[3] = (bf16_t)v.w;
  *(bf16x4*)(out + (size_t)i * 4) = o;
}

// ---------------- tokenize: x[b][c][s] -> t[b][s][c] (f32 + bf16) ----------------
__global__ __launch_bounds__(256) void tok_kernel(const float* __restrict__ x,
                                                  float* __restrict__ tf,
                                                  bf16_t* __restrict__ tb) {
  __shared__ float tile[32][33];
  int b = blockIdx.z;
  int c0 = blockIdx.y * 32, s0 = blockIdx.x * 32;
  int tx = threadIdx.x, ty = threadIdx.y;   // (32, 8)
  const float* xp = x + (size_t)b * CDIM * NTOK;
  for (int r = 0; r < 32; r += 8)
    tile[ty + r][tx] = xp[(size_t)(c0 + ty + r) * NTOK + s0 + tx];
  __syncthreads();
  float* tfp = tf + (size_t)b * NTOK * CDIM;
  bf16_t* tbp = tb + (size_t)b * NTOK * CDIM;
  for (int r = 0; r < 32; r += 8) {
    float v = tile[tx][ty + r];
    size_t idx = (size_t)(s0 + ty + r) * CDIM + c0 + tx;
    tfp[idx] = v;
    tbp[idx] = (bf16_t)v;
  }
}

// ---------------- LayerNorm: f32 in -> bf16 out ----------------
__global__ __launch_bounds__(64) void ln_kernel(const float* __restrict__ t,
                                                const float* __restrict__ g,
                                                const float* __restrict__ bt,
                                                bf16_t* __restrict__ out) {
  int row = blockIdx.x;
  int l = threadIdx.x;  // 64
  const float* x = t + (size_t)row * CDIM;
  float4 v0 = ((const float4*)x)[l];
  float4 v1 = ((const float4*)x)[l + 64];
  float s = v0.x + v0.y + v0.z + v0.w + v1.x + v1.y + v1.z + v1.w;
  float sq = v0.x*v0.x + v0.y*v0.y + v0.z*v0.z + v0.w*v0.w
           + v1.x*v1.x + v1.y*v1.y + v1.z*v1.z + v1.w*v1.w;
  for (int m = 1; m < 64; m <<= 1) { s += __shfl_xor(s, m); sq += __shfl_xor(sq, m); }
  float mean = s * (1.f / 512.f);
  float var = sq * (1.f / 512.f) - mean * mean;
  float rs = rsqrtf(var + 1e-5f);
  float4 g0 = ((const float4*)g)[l], g1 = ((const float4*)g)[l + 64];
  float4 b0 = ((const float4*)bt)[l], b1 = ((const float4*)bt)[l + 64];
  bf16x4 o0, o1;
  o0[0] = (bf16_t)((v0.x - mean) * rs * g0.x + b0.x);
  o0[1] = (bf16_t)((v0.y - mean) * rs * g0.y + b0.y);
  o0[2] = (bf16_t)((v0.z - mean) * rs * g0.z + b0.z);
  o0[3] = (bf16_t)((v0.w - mean) * rs * g0.w + b0.w);
  o1[0] = (bf16_t)((v1.x - mean) * rs * g1.x + b1.x);
  o1[1] = (bf16_t)((v1.y - mean) * rs * g1.y + b1.y);
  o1[2] = (bf16_t)((v1.z - mean) * rs * g1.z + b1.z);
  o1[3] = (bf16_t)((v1.w - mean) * rs * g1.w + b1.w);
  *(bf16x4*)(out + (size_t)row * CDIM + l * 4) = o0;
  *(bf16x4*)(out + (size_t)row * CDIM + 256 + l * 4) = o1;
}

// ---------------- GEMM: D[M][N] = A[M][512] * B[N][512]^T ----------------
// MODE 0: proj -> bf16 out [M][512], bias per col.
// MODE 1: out-head (A=W, B=tokens per batch) -> f32 out [b][512][1568],
//         bias/bn per row(=channel), relu+bn epilogue, col mask.
// MODE 2: V^T proj (A=Wv, B=tokens per batch) -> bf16 out [b][512][1568],
//         bias per row(=channel), col mask.
template<int MODE>
__global__ __launch_bounds__(256) void gemm_kernel(
    const bf16_t* __restrict__ A, const bf16_t* __restrict__ B,
    const float* __restrict__ bias, const float* __restrict__ bng,
    const float* __restrict__ bnb, bf16_t* __restrict__ outb,
    float* __restrict__ outf, int Nvalid) {
  int z = blockIdx.z;
  const bf16_t* Bp = B;
  float* outfp = outf;
  bf16_t* outbp = outb;
  if (MODE != 0) {
    Bp += (size_t)z * NTOK * CDIM;
    if (MODE == 1) outfp += (size_t)z * CDIM * NTOK;
    else outbp += (size_t)z * CDIM * NTOK;
  }
  int m0 = blockIdx.y * 128, n0 = blockIdx.x * 128;
  __shared__ bf16_t As[128][40];
  __shared__ bf16_t Bs[128][40];
  int tid = threadIdx.x;
  int w = tid >> 6, l = tid & 63, lr = l & 15, kg = l >> 4;
  int wm = (w >> 1) * 64, wn = (w & 1) * 64;
  f32x4 acc[4][4];
  for (int i = 0; i < 4; i++)
    for (int j = 0; j < 4; j++)
      acc[i][j] = f32x4{0.f, 0.f, 0.f, 0.f};
  int srow = tid >> 1;
  int soff = (tid & 1) * 16;
  int brow = n0 + srow;
  if (MODE != 0 && brow >= Nvalid) brow = Nvalid - 1;
  const bf16_t* aq = A + (size_t)(m0 + srow) * CDIM + soff;
  const bf16_t* bq = Bp + (size_t)brow * CDIM + soff;
  for (int kk = 0; kk < 16; kk++) {
    __syncthreads();
    bf16x8 a0 = *(const bf16x8*)(aq);
    bf16x8 a1 = *(const bf16x8*)(aq + 8);
    bf16x8 b0 = *(const bf16x8*)(bq);
    bf16x8 b1 = *(const bf16x8*)(bq + 8);
    aq += 32; bq += 32;
    *(bf16x8*)&As[srow][soff] = a0;
    *(bf16x8*)&As[srow][soff + 8] = a1;
    *(bf16x8*)&Bs[srow][soff] = b0;
    *(bf16x8*)&Bs[srow][soff + 8] = b1;
    __syncthreads();
    bf16x8 af[4], bfr[4];
    for (int i = 0; i < 4; i++) af[i] = *(const bf16x8*)&As[wm + i * 16 + lr][kg * 8];
    for (int j = 0; j < 4; j++) bfr[j] = *(const bf16x8*)&Bs[wn + j * 16 + lr][kg * 8];
    for (int i = 0; i < 4; i++)
      for (int j = 0; j < 4; j++)
        acc[i][j] = __builtin_amdgcn_mfma_f32_16x16x32_bf16(af[i], bfr[j], acc[i][j], 0, 0, 0);
  }
  for (int i = 0; i < 4; i++)
    for (int j = 0; j < 4; j++) {
      int rbase = m0 + wm + i * 16 + kg * 4;
      int col = n0 + wn + j * 16 + lr;
      for (int r = 0; r < 4; r++) {
        int row = rbase + r;
        float v = acc[i][j][r];
        if (MODE == 0) {
          v += bias[col];
          outbp[(size_t)row * CDIM + col] = (bf16_t)v;
        } else if (MODE == 1) {
          v += bias[row];
          v = v > 0.f ? v : 0.f;
          v *= RSQ1PEPS;
          v = v * bng[row] + bnb[row];
          if (col < Nvalid) outfp[(size_t)row * NTOK + col] = v;
        } else {
          v += bias[row];
          if (col < Nvalid) outbp[(size_t)row * NTOK + col] = (bf16_t)v;
        }
      }
    }
}

// ---------------- attention: swapped-operand flash, 4 waves x 32 q, KVB=32 ----------------
// S^T = mfma(K, Q): lane owns q = q0 + (lane&31); softmax lane-local + 1 shfl(32).
// O^T = mfma(V^T, P): accum col = q (lane-local rescale). V^T pre-transposed in global.
__global__ __launch_bounds__(256) void attn_kernel(
    const bf16_t* __restrict__ qg, const bf16_t* __restrict__ kgp,
    const bf16_t* __restrict__ vtg, float* __restrict__ tf, bf16_t* __restrict__ tb) {
  __shared__ alignas(16) bf16_t Ks[2][32][64];   // linear, XOR-swizzled by ((row&7)<<3) elems
  __shared__ alignas(16) bf16_t Vs[2][64][40];   // V^T tile [d][k], stride 80B (rotates bank quads)
  int b = blockIdx.z, h = blockIdx.y, qt = blockIdx.x;
  int tid = threadIdx.x, w = tid >> 6, l = tid & 63;
  int lo = l & 31, hi = l >> 5;
  const size_t kbase = ((size_t)b * NTOK) * CDIM + h * 64;
  const size_t vbase = ((size_t)b * CDIM + h * 64) * NTOK;

  // Q fragments: lane holds Q[q0+lo][c*16 + hi*8 + j]
  int q0 = qt * 128 + w * 32;
  int qrow = q0 + lo;
  int qr = qrow < NTOK ? qrow : NTOK - 1;
  const bf16_t* qp = qg + kbase + (size_t)qr * CDIM + hi * 8;
  bf16x8 qf[4];
  qf[0] = *(const bf16x8*)(qp);
  qf[1] = *(const bf16x8*)(qp + 16);
  qf[2] = *(const bf16x8*)(qp + 32);
  qf[3] = *(const bf16x8*)(qp + 48);

  // K staging (global_load_lds, pre-swizzled global source)
  int ksr = w * 8 + (l >> 3);                  // tile row this lane feeds
  int ksc = 8 * ((l & 7) ^ ((l >> 3) & 7));    // pre-swizzled source column (elems)
  const bf16_t* kgl = kgp + kbase + (size_t)ksr * CDIM + ksc;
  // V staging (reg -> LDS)
  int vd = tid >> 2, vc = (tid & 3) * 8;
  const bf16_t* vgl = vtg + vbase + (size_t)vd * NTOK + vc;

  float m_i = -1e30f, l_i = 0.f;
  f32x16 ot0, ot1;
#pragma unroll
  for (int r = 0; r < 16; r++) { ot0[r] = 0.f; ot1[r] = 0.f; }

  // prologue: stage tile 0
  __builtin_amdgcn_global_load_lds(
      (const __attribute__((address_space(1))) unsigned*)(kgl),
      (__attribute__((address_space(3))) unsigned*)&Ks[0][w * 8][0], 16, 0, 0);
  {
    bf16x8 vr = *(const bf16x8*)(vgl);
    *(bf16x8*)&Vs[0][vd][vc] = vr;
  }
  asm volatile("s_waitcnt vmcnt(0)" ::: "memory");
  __syncthreads();

  for (int kt = 0; kt < 49; kt++) {
    int cur = kt & 1, nxt = cur ^ 1;
    int ktn = kt + 1 < 49 ? kt + 1 : 48;
    // issue next-tile loads first (overlap with compute)
    __builtin_amdgcn_global_load_lds(
        (const __attribute__((address_space(1))) unsigned*)(kgl + (size_t)ktn * 32 * CDIM),
        (__attribute__((address_space(3))) unsigned*)&Ks[nxt][w * 8][0], 16, 0, 0);
    bf16x8 vr = *(const bf16x8*)(vgl + ktn * 32);

    // S^T[key][q] over this 32-key tile
    f32x16 st;
#pragma unroll
    for (int r = 0; r < 16; r++) st[r] = 0.f;
#pragma unroll
    for (int c = 0; c < 4; c++) {
      bf16x8 kf = *(const bf16x8*)&Ks[cur][lo][(c * 16 + hi * 8) ^ ((lo & 7) << 3)];
      st = __builtin_amdgcn_mfma_f32_32x32x16_bf16(kf, qf[c], st, 0, 0, 0);
    }
    // lane-local online softmax (q = q0+lo); lane holds 16 of 32 keys, partner = l^32
    float p[16];
    float tm = -1e30f;
#pragma unroll
    for (int r = 0; r < 16; r++) { p[r] = st[r] * 0.125f; tm = fmaxf(tm, p[r]); }
    tm = fmaxf(tm, __shfl_xor(tm, 32));
    float mn = fmaxf(m_i, tm);
    float alpha = __expf(m_i - mn);
    m_i = mn;
    float ts = 0.f;
#pragma unroll
    for (int r = 0; r < 16; r++) { p[r] = __expf(p[r] - mn); ts += p[r]; }
    ts += __shfl_xor(ts, 32);
    l_i = l_i * alpha + ts;
#pragma unroll
    for (int r = 0; r < 16; r++) { ot0[r] *= alpha; ot1[r] *= alpha; }
    // pack P to bf16 pairs, exchange halves with partner lane (l^32)
    unsigned pk[8];
#pragma unroll
    for (int g = 0; g < 8; g++) {
      union { bf16_t hh[2]; unsigned u; } cv;
      cv.hh[0] = (bf16_t)p[2 * g];
      cv.hh[1] = (bf16_t)p[2 * g + 1];
      pk[g] = cv.u;
    }
    unsigned x0 = __shfl_xor((int)pk[0], 32), x1 = __shfl_xor((int)pk[1], 32);
    unsigned x2 = __shfl_xor((int)pk[2], 32), x3 = __shfl_xor((int)pk[3], 32);
    unsigned x4 = __shfl_xor((int)pk[4], 32), x5 = __shfl_xor((int)pk[5], 32);
    unsigned x6 = __shfl_xor((int)pk[6], 32), x7 = __shfl_xor((int)pk[7], 32);
    union { u32x4 u; bf16x8 bv; } F0, F1;
    F0.u[0] = hi ? x2 : pk[0];
    F0.u[1] = hi ? x3 : pk[1];
    F0.u[2] = hi ? pk[2] : x0;
    F0.u[3] = hi ? pk[3] : x1;
    F1.u[0] = hi ? x6 : pk[4];
    F1.u[1] = hi ? x7 : pk[5];
    F1.u[2] = hi ? pk[6] : x4;
    F1.u[3] = hi ? pk[7] : x5;
    // O^T += V^T * P  (A = V^T rows from LDS, B = P frags in regs)
    {
      bf16x8 v0 = *(const bf16x8*)&Vs[cur][lo][hi * 8];
      ot0 = __builtin_amdgcn_mfma_f32_32x32x16_bf16(v0, F0.bv, ot0, 0, 0, 0);
      bf16x8 v1 = *(const bf16x8*)&Vs[cur][lo][16 + hi * 8];
      ot0 = __builtin_amdgcn_mfma_f32_32x32x16_bf16(v1, F1.bv, ot0, 0, 0, 0);
      bf16x8 v2 = *(const bf16x8*)&Vs[cur][32 + lo][hi * 8];
      ot1 = __builtin_amdgcn_mfma_f32_32x32x16_bf16(v2, F0.bv, ot1, 0, 0, 0);
      bf16x8 v3 = *(const bf16x8*)&Vs[cur][32 + lo][16 + hi * 8];
      ot1 = __builtin_amdgcn_mfma_f32_32x32x16_bf16(v3, F1.bv, ot1, 0, 0, 0);
    }
    // land prefetch, publish V tile
    *(bf16x8*)&Vs[nxt][vd][vc] = vr;
    asm volatile("s_waitcnt vmcnt(0)" ::: "memory");
    __syncthreads();
  }

  // epilogue: O^T/l + residual; lane q = q0+lo, d = db*32 + g*8 + hi*4 + rr
  if (qrow < NTOK) {
    float inv = 1.f / l_i;
    float* tfp = tf + ((size_t)b * NTOK + qrow) * CDIM + h * 64 + hi * 4;
    bf16_t* tbp = tb + ((size_t)b * NTOK + qrow) * CDIM + h * 64 + hi * 4;
#pragma unroll
    for (int db = 0; db < 2; db++) {
#pragma unroll
      for (int g = 0; g < 4; g++) {
        int doff = db * 32 + g * 8;
        float4 old = *(float4*)(tfp + doff);
        float4 nv;
        float a0 = (db ? ot1[g * 4 + 0] : ot0[g * 4 + 0]) * inv;
        float a1 = (db ? ot1[g * 4 + 1] : ot0[g * 4 + 1]) * inv;
        float a2 = (db ? ot1[g * 4 + 2] : ot0[g * 4 + 2]) * inv;
        float a3 = (db ? ot1[g * 4 + 3] : ot0[g * 4 + 3]) * inv;
        nv.x = old.x + a0; nv.y = old.y + a1; nv.z = old.z + a2; nv.w = old.w + a3;
        *(float4*)(tfp + doff) = nv;
        bf16x4 ob;
        ob[0] = (bf16_t)nv.x; ob[1] = (bf16_t)nv.y;
        ob[2] = (bf16_t)nv.z; ob[3] = (bf16_t)nv.w;
        *(bf16x4*)(tbp + doff) = ob;
      }
    }
  }
}

extern "C" void kernel_launch(void* const* d_in, const int* in_sizes, int n_in,
                              void* d_out, int out_size, void* d_ws, size_t ws_size,
                              hipStream_t stream) {
  (void)in_sizes; (void)n_in; (void)out_size; (void)ws_size;
  const float* x1 = (const float*)d_in[0];
  const float* x2 = (const float*)d_in[1];
  const float* Wq1 = (const float*)d_in[2];
  const float* bq1 = (const float*)d_in[3];
  const float* Wk1 = (const float*)d_in[4];
  const float* bk1 = (const float*)d_in[5];
  const float* Wv1 = (const float*)d_in[6];
  const float* bv1 = (const float*)d_in[7];
  const float* ln1_g = (const float*)d_in[8];
  const float* ln1_b = (const float*)d_in[9];
  const float* Wq2 = (const float*)d_in[10];
  const float* bq2 = (const float*)d_in[11];
  const float* Wk2 = (const float*)d_in[12];
  const float* bk2 = (const float*)d_in[13];
  const float* Wv2 = (const float*)d_in[14];
  const float* bv2 = (const float*)d_in[15];
  const float* ln2_g = (const float*)d_in[16];
  const float* ln2_b = (const float*)d_in[17];
  const float* out1_w = (const float*)d_in[18];
  const float* out1_b = (const float*)d_in[19];
  const float* bn1_g = (const float*)d_in[20];
  const float* bn1_b = (const float*)d_in[21];
  const float* out2_w = (const float*)d_in[22];
  const float* out2_b = (const float*)d_in[23];
  const float* bn2_g = (const float*)d_in[24];
  const float* bn2_b = (const float*)d_in[25];

  const size_t WMAT = 512 * 512;            // elems per weight matrix
  char* ws = (char*)d_ws;
  bf16_t* wb = (bf16_t*)ws;                 // 20 matrices bf16
  size_t off = 20 * WMAT * sizeof(bf16_t);
  float* t1f = (float*)(ws + off); off += (size_t)MROWS * CDIM * 4;
  float* t2f = (float*)(ws + off); off += (size_t)MROWS * CDIM * 4;
  bf16_t* t1b = (bf16_t*)(ws + off); off += (size_t)MROWS * CDIM * 2;
  bf16_t* t2b = (bf16_t*)(ws + off); off += (size_t)MROWS * CDIM * 2;
  bf16_t* l1b = (bf16_t*)(ws + off); off += (size_t)MROWS * CDIM * 2;
  bf16_t* l2b = (bf16_t*)(ws + off); off += (size_t)MROWS * CDIM * 2;
  bf16_t* q1b = (bf16_t*)(ws + off); off += (size_t)MROWS * CDIM * 2;
  bf16_t* k1b = (bf16_t*)(ws + off); off += (size_t)MROWS * CDIM * 2;
  bf16_t* v1b = (bf16_t*)(ws + off); off += (size_t)MROWS * CDIM * 2;  // V^T layout [b][512][1568]
  bf16_t* q2b = (bf16_t*)(ws + off); off += (size_t)MROWS * CDIM * 2;
  bf16_t* k2b = (bf16_t*)(ws + off); off += (size_t)MROWS * CDIM * 2;
  bf16_t* v2b = (bf16_t*)(ws + off); off += (size_t)MROWS * CDIM * 2;  // V^T layout

  cast_kernel<<<768, 256, 0, stream>>>(Wq1, wb + 0 * WMAT);
  cast_kernel<<<768, 256, 0, stream>>>(Wk1, wb + 3 * WMAT);
  cast_kernel<<<768, 256, 0, stream>>>(Wv1, wb + 6 * WMAT);
  cast_kernel<<<768, 256, 0, stream>>>(Wq2, wb + 9 * WMAT);
  cast_kernel<<<768, 256, 0, stream>>>(Wk2, wb + 12 * WMAT);
  cast_kernel<<<768, 256, 0, stream>>>(Wv2, wb + 15 * WMAT);
  cast_kernel<<<256, 256, 0, stream>>>(out1_w, wb + 18 * WMAT);
  cast_kernel<<<256, 256, 0, stream>>>(out2_w, wb + 19 * WMAT);

  tok_kernel<<<dim3(49, 16, 4), dim3(32, 8), 0, stream>>>(x1, t1f, t1b);
  tok_kernel<<<dim3(49, 16, 4), dim3(32, 8), 0, stream>>>(x2, t2f, t2b);

  dim3 gp(4, 49, 1);       // MODE 0 proj
  dim3 gv(13, 4, 4);       // MODE 2 V^T proj
  dim3 ga(13, 8, 4);       // attention
  for (int i = 0; i < 3; i++) {
    ln_kernel<<<6272, 64, 0, stream>>>(t1f, ln1_g + i * 512, ln1_b + i * 512, l1b);
    ln_kernel<<<6272, 64, 0, stream>>>(t2f, ln2_g + i * 512, ln2_b + i * 512, l2b);
    gemm_kernel<0><<<gp, 256, 0, stream>>>(l1b, wb + (0 + i) * WMAT, bq1 + i * 512,
                                           nullptr, nullptr, q1b, nullptr, 512);
    gemm_kernel<0><<<gp, 256, 0, stream>>>(t2b, wb + (3 + i) * WMAT, bk1 + i * 512,
                                           nullptr, nullptr, k1b, nullptr, 512);
    gemm_kernel<2><<<gv, 256, 0, stream>>>(wb + (6 + i) * WMAT, t2b, bv1 + i * 512,
                                           nullptr, nullptr, v1b, nullptr, NTOK);
    gemm_kernel<0><<<gp, 256, 0, stream>>>(l2b, wb + (9 + i) * WMAT, bq2 + i * 512,
                                           nullptr, nullptr, q2b, nullptr, 512);
    gemm_kernel<0><<<gp, 256, 0, stream>>>(t1b, wb + (12 + i) * WMAT, bk2 + i * 512,
                                           nullptr, nullptr, k2b, nullptr, 512);
    gemm_kernel<2><<<gv, 256, 0, stream>>>(wb + (15 + i) * WMAT, t1b, bv2 + i * 512,
                                           nullptr, nullptr, v2b, nullptr, NTOK);
    attn_kernel<<<ga, 256, 0, stream>>>(q1b, k1b, v1b, t1f, t1b);
    attn_kernel<<<ga, 256, 0, stream>>>(q2b, k2b, v2b, t2f, t2b);
  }

  float* out = (float*)d_out;
  dim3 gh(13, 4, 4);
  gemm_kernel<1><<<gh, 256, 0, stream>>>(wb + 18 * WMAT, t1b, out1_b, bn1_g, bn1_b,
                                         nullptr, out, NTOK);
  gemm_kernel<1><<<gh, 256, 0, stream>>>(wb + 19 * WMAT, t2b, out2_b, bn2_g, bn2_b,
                                         nullptr, out + (size_t)BATCH * CDIM * NTOK, NTOK);
}

// Round 3
// 525.119 us; speedup vs baseline: 2.5988x; 1.5971x over previous
//
#include <hip/hip_runtime.h>

typedef __bf16 bf16_t;
typedef __bf16 bf16x8 __attribute__((ext_vector_type(8)));
typedef __bf16 bf16x4 __attribute__((ext_vector_type(4)));
typedef float f32x4 __attribute__((ext_vector_type(4)));
typedef float f32x16 __attribute__((ext_vector_type(16)));
typedef unsigned u32x4 __attribute__((ext_vector_type(4)));

#define NTOK 1568
#define CDIM 512
#define BATCH 4
#define MROWS (BATCH*NTOK)  // 6272
#define RSQ1PEPS 0.9999950000374997f
#define CEXP 0.1803368801111204f   // 0.125 * log2(e)
#define DEFER_THR 44.3614195558365f // 8 / CEXP

__device__ __forceinline__ float fexp2(float x) {
  float r;
  asm("v_exp_f32 %0, %1" : "=v"(r) : "v"(x));
  return r;
}

// ---------------- cast all weights f32 -> bf16 (one launch) ----------------
struct CastArgs { const float* s[20]; };
__global__ __launch_bounds__(256) void cast_kernel(CastArgs ca, bf16_t* __restrict__ out) {
  int idx = blockIdx.x * 256 + threadIdx.x;   // float4 index over 20*65536
  int m = idx >> 16;
  const float4* sp = (const float4*)ca.s[m];
  float4 v = sp[idx & 65535];
  bf16x4 o;
  o[0] = (bf16_t)v.x; o[1] = (bf16_t)v.y; o[2] = (bf16_t)v.z; o[3] = (bf16_t)v.w;
  *(bf16x4*)(out + (size_t)idx * 4) = o;
}

// ---------------- tokenize both inputs: x[b][c][s] -> t[b][s][c] ----------------
struct TokArgs { const float* x[2]; float* tf[2]; bf16_t* tb[2]; };
__global__ __launch_bounds__(256) void tok_kernel(TokArgs ta) {
  __shared__ float tile[32][33];
  int z = blockIdx.z, sel = z >> 2, b = z & 3;
  int c0 = blockIdx.y * 32, s0 = blockIdx.x * 32;
  int tx = threadIdx.x, ty = threadIdx.y;   // (32, 8)
  const float* xp = ta.x[sel] + (size_t)b * CDIM * NTOK;
  for (int r = 0; r < 32; r += 8)
    tile[ty + r][tx] = xp[(size_t)(c0 + ty + r) * NTOK + s0 + tx];
  __syncthreads();
  float* tfp = ta.tf[sel] + (size_t)b * NTOK * CDIM;
  bf16_t* tbp = ta.tb[sel] + (size_t)b * NTOK * CDIM;
  for (int r = 0; r < 32; r += 8) {
    float v = tile[tx][ty + r];
    size_t idx = (size_t)(s0 + ty + r) * CDIM + c0 + tx;
    tfp[idx] = v;
    tbp[idx] = (bf16_t)v;
  }
}

// ---------------- LayerNorm both streams: f32 in -> bf16 out ----------------
__global__ __launch_bounds__(64) void ln_kernel(
    const float* __restrict__ t1, const float* __restrict__ t2,
    const float* __restrict__ g1, const float* __restrict__ b1,
    const float* __restrict__ g2, const float* __restrict__ b2,
    bf16_t* __restrict__ o1, bf16_t* __restrict__ o2) {
  int row = blockIdx.x;
  const float* t; const float* g; const float* bt; bf16_t* out;
  if (row < MROWS) { t = t1; g = g1; bt = b1; out = o1; }
  else { row -= MROWS; t = t2; g = g2; bt = b2; out = o2; }
  int l = threadIdx.x;  // 64
  const float* x = t + (size_t)row * CDIM;
  float4 v0 = ((const float4*)x)[l];
  float4 v1 = ((const float4*)x)[l + 64];
  float s = v0.x + v0.y + v0.z + v0.w + v1.x + v1.y + v1.z + v1.w;
  float sq = v0.x*v0.x + v0.y*v0.y + v0.z*v0.z + v0.w*v0.w
           + v1.x*v1.x + v1.y*v1.y + v1.z*v1.z + v1.w*v1.w;
  for (int m = 1; m < 64; m <<= 1) { s += __shfl_xor(s, m); sq += __shfl_xor(sq, m); }
  float mean = s * (1.f / 512.f);
  float var = sq * (1.f / 512.f) - mean * mean;
  float rs = rsqrtf(var + 1e-5f);
  float4 g0 = ((const float4*)g)[l], g1v = ((const float4*)g)[l + 64];
  float4 b0 = ((const float4*)bt)[l], b1v = ((const float4*)bt)[l + 64];
  bf16x4 o0, o1v;
  o0[0] = (bf16_t)((v0.x - mean) * rs * g0.x + b0.x);
  o0[1] = (bf16_t)((v0.y - mean) * rs * g0.y + b0.y);
  o0[2] = (bf16_t)((v0.z - mean) * rs * g0.z + b0.z);
  o0[3] = (bf16_t)((v0.w - mean) * rs * g0.w + b0.w);
  o1v[0] = (bf16_t)((v1.x - mean) * rs * g1v.x + b1v.x);
  o1v[1] = (bf16_t)((v1.y - mean) * rs * g1v.y + b1v.y);
  o1v[2] = (bf16_t)((v1.z - mean) * rs * g1v.z + b1v.z);
  o1v[3] = (bf16_t)((v1.w - mean) * rs * g1v.w + b1v.w);
  *(bf16x4*)(out + (size_t)row * CDIM + l * 4) = o0;
  *(bf16x4*)(out + (size_t)row * CDIM + 256 + l * 4) = o1v;
}

// ---------------- shared GEMM core: D = A[M][512] * B[N][512]^T ----------------
// MODE 0: bf16 out [row*CDIM+col], bias per col, no mask.
// MODE 1: f32 out [row*NTOK+col], bias/relu/bn per row, col mask.
// MODE 2: bf16 out [row*NTOK+col], bias per row, col mask.
template<int MODE>
__device__ __forceinline__ void gemm_core(
    bf16_t (* __restrict__ As)[40], bf16_t (* __restrict__ Bs)[40],
    const bf16_t* __restrict__ A, const bf16_t* __restrict__ Bp,
    const float* __restrict__ bias, const float* __restrict__ bng,
    const float* __restrict__ bnb, bf16_t* __restrict__ outb,
    float* __restrict__ outf, int m0, int n0, int Nvalid) {
  int tid = threadIdx.x;
  int w = tid >> 6, l = tid & 63, lr = l & 15, kg = l >> 4;
  int wm = (w >> 1) * 64, wn = (w & 1) * 64;
  f32x4 acc[4][4];
  for (int i = 0; i < 4; i++)
    for (int j = 0; j < 4; j++)
      acc[i][j] = f32x4{0.f, 0.f, 0.f, 0.f};
  int srow = tid >> 1;
  int soff = (tid & 1) * 16;
  int brow = n0 + srow;
  if (MODE != 0 && brow >= Nvalid) brow = Nvalid - 1;
  const bf16_t* aq = A + (size_t)(m0 + srow) * CDIM + soff;
  const bf16_t* bq = Bp + (size_t)brow * CDIM + soff;
  for (int kk = 0; kk < 16; kk++) {
    __syncthreads();
    bf16x8 a0 = *(const bf16x8*)(aq);
    bf16x8 a1 = *(const bf16x8*)(aq + 8);
    bf16x8 b0 = *(const bf16x8*)(bq);
    bf16x8 b1 = *(const bf16x8*)(bq + 8);
    aq += 32; bq += 32;
    *(bf16x8*)&As[srow][soff] = a0;
    *(bf16x8*)&As[srow][soff + 8] = a1;
    *(bf16x8*)&Bs[srow][soff] = b0;
    *(bf16x8*)&Bs[srow][soff + 8] = b1;
    __syncthreads();
    bf16x8 af[4], bfr[4];
    for (int i = 0; i < 4; i++) af[i] = *(const bf16x8*)&As[wm + i * 16 + lr][kg * 8];
    for (int j = 0; j < 4; j++) bfr[j] = *(const bf16x8*)&Bs[wn + j * 16 + lr][kg * 8];
    for (int i = 0; i < 4; i++)
      for (int j = 0; j < 4; j++)
        acc[i][j] = __builtin_amdgcn_mfma_f32_16x16x32_bf16(af[i], bfr[j], acc[i][j], 0, 0, 0);
  }
  for (int i = 0; i < 4; i++)
    for (int j = 0; j < 4; j++) {
      int rbase = m0 + wm + i * 16 + kg * 4;
      int col = n0 + wn + j * 16 + lr;
      for (int r = 0; r < 4; r++) {
        int row = rbase + r;
        float v = acc[i][j][r];
        if (MODE == 0) {
          v += bias[col];
          outb[(size_t)row * CDIM + col] = (bf16_t)v;
        } else if (MODE == 1) {
          v += bias[row];
          v = v > 0.f ? v : 0.f;
          v *= RSQ1PEPS;
          v = v * bng[row] + bnb[row];
          if (col < Nvalid) outf[(size_t)row * NTOK + col] = v;
        } else {
          v += bias[row];
          if (col < Nvalid) outb[(size_t)row * NTOK + col] = (bf16_t)v;
        }
      }
    }
}

// ---------------- fused per-stage projections: 4x MODE0 (q1,k1,q2,k2) + 2x MODE2 (v1T,v2T) ----------------
struct ProjArgs {
  const bf16_t* A0[4]; const bf16_t* W0[4]; const float* b0[4]; bf16_t* o0[4];
  const bf16_t* W2[2]; const bf16_t* B2[2]; const float* b2[2]; bf16_t* o2[2];
};
__global__ __launch_bounds__(256) void proj_kernel(ProjArgs p) {
  __shared__ bf16_t As[128][40];
  __shared__ bf16_t Bs[128][40];
  int id = blockIdx.x;
  if (id < 784) {
    int set = id / 196, rem = id % 196;
    int n0 = (rem & 3) * 128, m0 = (rem >> 2) * 128;
    gemm_core<0>(As, Bs, p.A0[set], p.W0[set], p.b0[set], nullptr, nullptr,
                 p.o0[set], nullptr, m0, n0, 512);
  } else {
    int j = id - 784;
    int unit = j / 52;             // 0..7
    int which = unit >> 2, bat = unit & 3;
    int rem = j % 52;
    int n0 = (rem % 13) * 128, m0 = (rem / 13) * 128;
    gemm_core<2>(As, Bs, p.W2[which], p.B2[which] + (size_t)bat * NTOK * CDIM,
                 p.b2[which], nullptr, nullptr,
                 p.o2[which] + (size_t)bat * CDIM * NTOK, nullptr, m0, n0, NTOK);
  }
}

// ---------------- fused out-heads (MODE 1) ----------------
__global__ __launch_bounds__(256) void head_kernel(
    const bf16_t* __restrict__ W1, const bf16_t* __restrict__ W2,
    const bf16_t* __restrict__ t1b, const bf16_t* __restrict__ t2b,
    const float* __restrict__ b1, const float* __restrict__ b2,
    const float* __restrict__ bng1, const float* __restrict__ bnb1,
    const float* __restrict__ bng2, const float* __restrict__ bnb2,
    float* __restrict__ out) {
  __shared__ bf16_t As[128][40];
  __shared__ bf16_t Bs[128][40];
  int z = blockIdx.z;
  int which = z >> 2, bat = z & 3;
  const bf16_t* A = which ? W2 : W1;
  const bf16_t* Bp = (which ? t2b : t1b) + (size_t)bat * NTOK * CDIM;
  const float* bias = which ? b2 : b1;
  const float* bng = which ? bng2 : bng1;
  const float* bnb = which ? bnb2 : bnb1;
  float* outf = out + (size_t)which * BATCH * CDIM * NTOK + (size_t)bat * CDIM * NTOK;
  int m0 = blockIdx.y * 128, n0 = blockIdx.x * 128;
  gemm_core<1>(As, Bs, A, Bp, bias, bng, bnb, nullptr, outf, m0, n0, NTOK);
}

// ---------------- fused attention (both streams), swapped-operand flash ----------------
struct AttnArgs {
  const bf16_t* q[2]; const bf16_t* k[2]; const bf16_t* v[2];
  float* tf[2]; bf16_t* tb[2];
};
__global__ __launch_bounds__(256) void attn_kernel(AttnArgs aa) {
  __shared__ alignas(16) bf16_t Ks[2][32][64];   // XOR-swizzled by ((row&7)<<3) elems
  __shared__ alignas(16) bf16_t Vs[2][64][40];   // V^T tile [d][k], stride 80B
  int z = blockIdx.z, s = z >> 2, b = z & 3;
  int h = blockIdx.y, qt = blockIdx.x;
  const bf16_t* qg = aa.q[s];
  const bf16_t* kgp = aa.k[s];
  const bf16_t* vtg = aa.v[s];
  float* tf = aa.tf[s];
  bf16_t* tb = aa.tb[s];
  int tid = threadIdx.x, w = tid >> 6, l = tid & 63;
  int lo = l & 31, hi = l >> 5;
  const size_t kbase = ((size_t)b * NTOK) * CDIM + h * 64;
  const size_t vbase = ((size_t)b * CDIM + h * 64) * NTOK;

  int q0 = qt * 128 + w * 32;
  int qrow = q0 + lo;
  int qr = qrow < NTOK ? qrow : NTOK - 1;
  const bf16_t* qp = qg + kbase + (size_t)qr * CDIM + hi * 8;
  bf16x8 qf[4];
  qf[0] = *(const bf16x8*)(qp);
  qf[1] = *(const bf16x8*)(qp + 16);
  qf[2] = *(const bf16x8*)(qp + 32);
  qf[3] = *(const bf16x8*)(qp + 48);

  int ksr = w * 8 + (l >> 3);
  int ksc = 8 * ((l & 7) ^ ((l >> 3) & 7));
  const bf16_t* kgl = kgp + kbase + (size_t)ksr * CDIM + ksc;
  int vd = tid >> 2, vc = (tid & 3) * 8;
  const bf16_t* vgl = vtg + vbase + (size_t)vd * NTOK + vc;

  float m_i = -3.0e38f, l_i = 0.f;
  f32x16 ot0, ot1;
#pragma unroll
  for (int r = 0; r < 16; r++) { ot0[r] = 0.f; ot1[r] = 0.f; }

  __builtin_amdgcn_global_load_lds(
      (const __attribute__((address_space(1))) unsigned*)(kgl),
      (__attribute__((address_space(3))) unsigned*)&Ks[0][w * 8][0], 16, 0, 0);
  {
    bf16x8 vr = *(const bf16x8*)(vgl);
    *(bf16x8*)&Vs[0][vd][vc] = vr;
  }
  asm volatile("s_waitcnt vmcnt(0)" ::: "memory");
  __syncthreads();

  for (int kt = 0; kt < 49; kt++) {
    int cur = kt & 1, nxt = cur ^ 1;
    int ktn = kt + 1 < 49 ? kt + 1 : 48;
    __builtin_amdgcn_global_load_lds(
        (const __attribute__((address_space(1))) unsigned*)(kgl + (size_t)ktn * 32 * CDIM),
        (__attribute__((address_space(3))) unsigned*)&Ks[nxt][w * 8][0], 16, 0, 0);
    bf16x8 vr = *(const bf16x8*)(vgl + ktn * 32);

    // S^T[key][q] raw (scale folded into exp)
    f32x16 st;
#pragma unroll
    for (int r = 0; r < 16; r++) st[r] = 0.f;
#pragma unroll
    for (int c = 0; c < 4; c++) {
      bf16x8 kf = *(const bf16x8*)&Ks[cur][lo][(c * 16 + hi * 8) ^ ((lo & 7) << 3)];
      st = __builtin_amdgcn_mfma_f32_32x32x16_bf16(kf, qf[c], st, 0, 0, 0);
    }
    // online softmax, lane-local q = q0+lo; defer-max rescale
    float tm = st[0];
#pragma unroll
    for (int r = 1; r < 16; r++) tm = fmaxf(tm, st[r]);
    tm = fmaxf(tm, __shfl_xor(tm, 32));
    if (!__all(tm <= m_i + DEFER_THR)) {
      float mn = fmaxf(m_i, tm);
      float alpha = fexp2((m_i - mn) * CEXP);
#pragma unroll
      for (int r = 0; r < 16; r++) { ot0[r] *= alpha; ot1[r] *= alpha; }
      l_i *= alpha;
      m_i = mn;
    }
    float nmC = -m_i * CEXP;
    float p[16];
    float ts = 0.f;
#pragma unroll
    for (int r = 0; r < 16; r++) { p[r] = fexp2(fmaf(st[r], CEXP, nmC)); ts += p[r]; }
    ts += __shfl_xor(ts, 32);
    l_i += ts;
    // pack P to bf16 pairs, exchange halves with partner lane (l^32)
    unsigned pk[8];
#pragma unroll
    for (int g = 0; g < 8; g++) {
      union { bf16_t hh[2]; unsigned u; } cv;
      cv.hh[0] = (bf16_t)p[2 * g];
      cv.hh[1] = (bf16_t)p[2 * g + 1];
      pk[g] = cv.u;
    }
    unsigned x0 = __shfl_xor((int)pk[0], 32), x1 = __shfl_xor((int)pk[1], 32);
    unsigned x2 = __shfl_xor((int)pk[2], 32), x3 = __shfl_xor((int)pk[3], 32);
    unsigned x4 = __shfl_xor((int)pk[4], 32), x5 = __shfl_xor((int)pk[5], 32);
    unsigned x6 = __shfl_xor((int)pk[6], 32), x7 = __shfl_xor((int)pk[7], 32);
    union { u32x4 u; bf16x8 bv; } F0, F1;
    F0.u[0] = hi ? x2 : pk[0];
    F0.u[1] = hi ? x3 : pk[1];
    F0.u[2] = hi ? pk[2] : x0;
    F0.u[3] = hi ? pk[3] : x1;
    F1.u[0] = hi ? x6 : pk[4];
    F1.u[1] = hi ? x7 : pk[5];
    F1.u[2] = hi ? pk[6] : x4;
    F1.u[3] = hi ? pk[7] : x5;
    // O^T += V^T * P
    {
      bf16x8 v0 = *(const bf16x8*)&Vs[cur][lo][hi * 8];
      ot0 = __builtin_amdgcn_mfma_f32_32x32x16_bf16(v0, F0.bv, ot0, 0, 0, 0);
      bf16x8 v1 = *(const bf16x8*)&Vs[cur][lo][16 + hi * 8];
      ot0 = __builtin_amdgcn_mfma_f32_32x32x16_bf16(v1, F1.bv, ot0, 0, 0, 0);
      bf16x8 v2 = *(const bf16x8*)&Vs[cur][32 + lo][hi * 8];
      ot1 = __builtin_amdgcn_mfma_f32_32x32x16_bf16(v2, F0.bv, ot1, 0, 0, 0);
      bf16x8 v3 = *(const bf16x8*)&Vs[cur][32 + lo][16 + hi * 8];
      ot1 = __builtin_amdgcn_mfma_f32_32x32x16_bf16(v3, F1.bv, ot1, 0, 0, 0);
    }
    *(bf16x8*)&Vs[nxt][vd][vc] = vr;
    asm volatile("s_waitcnt vmcnt(0)" ::: "memory");
    __syncthreads();
  }

  if (qrow < NTOK) {
    float inv = 1.f / l_i;
    float* tfp = tf + ((size_t)b * NTOK + qrow) * CDIM + h * 64 + hi * 4;
    bf16_t* tbp = tb + ((size_t)b * NTOK + qrow) * CDIM + h * 64 + hi * 4;
#pragma unroll
    for (int db = 0; db < 2; db++) {
#pragma unroll
      for (int g = 0; g < 4; g++) {
        int doff = db * 32 + g * 8;
        float4 old = *(float4*)(tfp + doff);
        float4 nv;
        float a0 = (db ? ot1[g * 4 + 0] : ot0[g * 4 + 0]) * inv;
        float a1 = (db ? ot1[g * 4 + 1] : ot0[g * 4 + 1]) * inv;
        float a2 = (db ? ot1[g * 4 + 2] : ot0[g * 4 + 2]) * inv;
        float a3 = (db ? ot1[g * 4 + 3] : ot0[g * 4 + 3]) * inv;
        nv.x = old.x + a0; nv.y = old.y + a1; nv.z = old.z + a2; nv.w = old.w + a3;
        *(float4*)(tfp + doff) = nv;
        bf16x4 ob;
        ob[0] = (bf16_t)nv.x; ob[1] = (bf16_t)nv.y;
        ob[2] = (bf16_t)nv.z; ob[3] = (bf16_t)nv.w;
        *(bf16x4*)(tbp + doff) = ob;
      }
    }
  }
}

extern "C" void kernel_launch(void* const* d_in, const int* in_sizes, int n_in,
                              void* d_out, int out_size, void* d_ws, size_t ws_size,
                              hipStream_t stream) {
  (void)in_sizes; (void)n_in; (void)out_size; (void)ws_size;
  const float* x1 = (const float*)d_in[0];
  const float* x2 = (const float*)d_in[1];
  const float* Wq1 = (const float*)d_in[2];
  const float* bq1 = (const float*)d_in[3];
  const float* Wk1 = (const float*)d_in[4];
  const float* bk1 = (const float*)d_in[5];
  const float* Wv1 = (const float*)d_in[6];
  const float* bv1 = (const float*)d_in[7];
  const float* ln1_g = (const float*)d_in[8];
  const float* ln1_b = (const float*)d_in[9];
  const float* Wq2 = (const float*)d_in[10];
  const float* bq2 = (const float*)d_in[11];
  const float* Wk2 = (const float*)d_in[12];
  const float* bk2 = (const float*)d_in[13];
  const float* Wv2 = (const float*)d_in[14];
  const float* bv2 = (const float*)d_in[15];
  const float* ln2_g = (const float*)d_in[16];
  const float* ln2_b = (const float*)d_in[17];
  const float* out1_w = (const float*)d_in[18];
  const float* out1_b = (const float*)d_in[19];
  const float* bn1_g = (const float*)d_in[20];
  const float* bn1_b = (const float*)d_in[21];
  const float* out2_w = (const float*)d_in[22];
  const float* out2_b = (const float*)d_in[23];
  const float* bn2_g = (const float*)d_in[24];
  const float* bn2_b = (const float*)d_in[25];

  const size_t WMAT = 512 * 512;
  char* ws = (char*)d_ws;
  bf16_t* wb = (bf16_t*)ws;
  size_t off = 20 * WMAT * sizeof(bf16_t);
  float* t1f = (float*)(ws + off); off += (size_t)MROWS * CDIM * 4;
  float* t2f = (float*)(ws + off); off += (size_t)MROWS * CDIM * 4;
  bf16_t* t1b = (bf16_t*)(ws + off); off += (size_t)MROWS * CDIM * 2;
  bf16_t* t2b = (bf16_t*)(ws + off); off += (size_t)MROWS * CDIM * 2;
  bf16_t* l1b = (bf16_t*)(ws + off); off += (size_t)MROWS * CDIM * 2;
  bf16_t* l2b = (bf16_t*)(ws + off); off += (size_t)MROWS * CDIM * 2;
  bf16_t* q1b = (bf16_t*)(ws + off); off += (size_t)MROWS * CDIM * 2;
  bf16_t* k1b = (bf16_t*)(ws + off); off += (size_t)MROWS * CDIM * 2;
  bf16_t* v1b = (bf16_t*)(ws + off); off += (size_t)MROWS * CDIM * 2;  // V^T [b][512][1568]
  bf16_t* q2b = (bf16_t*)(ws + off); off += (size_t)MROWS * CDIM * 2;
  bf16_t* k2b = (bf16_t*)(ws + off); off += (size_t)MROWS * CDIM * 2;
  bf16_t* v2b = (bf16_t*)(ws + off); off += (size_t)MROWS * CDIM * 2;  // V^T

  // cast all 20 weight matrices in one launch
  CastArgs ca;
  for (int i = 0; i < 3; i++) {
    ca.s[0 + i] = Wq1 + (size_t)i * WMAT;
    ca.s[3 + i] = Wk1 + (size_t)i * WMAT;
    ca.s[6 + i] = Wv1 + (size_t)i * WMAT;
    ca.s[9 + i] = Wq2 + (size_t)i * WMAT;
    ca.s[12 + i] = Wk2 + (size_t)i * WMAT;
    ca.s[15 + i] = Wv2 + (size_t)i * WMAT;
  }
  ca.s[18] = out1_w;
  ca.s[19] = out2_w;
  cast_kernel<<<5120, 256, 0, stream>>>(ca, wb);

  TokArgs ta;
  ta.x[0] = x1; ta.x[1] = x2;
  ta.tf[0] = t1f; ta.tf[1] = t2f;
  ta.tb[0] = t1b; ta.tb[1] = t2b;
  tok_kernel<<<dim3(49, 16, 8), dim3(32, 8), 0, stream>>>(ta);

  AttnArgs aa;
  aa.q[0] = q1b; aa.q[1] = q2b;
  aa.k[0] = k1b; aa.k[1] = k2b;
  aa.v[0] = v1b; aa.v[1] = v2b;
  aa.tf[0] = t1f; aa.tf[1] = t2f;
  aa.tb[0] = t1b; aa.tb[1] = t2b;

  for (int i = 0; i < 3; i++) {
    ln_kernel<<<2 * MROWS, 64, 0, stream>>>(t1f, t2f,
        ln1_g + i * 512, ln1_b + i * 512, ln2_g + i * 512, ln2_b + i * 512,
        l1b, l2b);
    ProjArgs pa;
    pa.A0[0] = l1b; pa.W0[0] = wb + (0 + i) * WMAT; pa.b0[0] = bq1 + i * 512; pa.o0[0] = q1b;
    pa.A0[1] = t2b; pa.W0[1] = wb + (3 + i) * WMAT; pa.b0[1] = bk1 + i * 512; pa.o0[1] = k1b;
    pa.A0[2] = l2b; pa.W0[2] = wb + (9 + i) * WMAT; pa.b0[2] = bq2 + i * 512; pa.o0[2] = q2b;
    pa.A0[3] = t1b; pa.W0[3] = wb + (12 + i) * WMAT; pa.b0[3] = bk2 + i * 512; pa.o0[3] = k2b;
    pa.W2[0] = wb + (6 + i) * WMAT; pa.B2[0] = t2b; pa.b2[0] = bv1 + i * 512; pa.o2[0] = v1b;
    pa.W2[1] = wb + (15 + i) * WMAT; pa.B2[1] = t1b; pa.b2[1] = bv2 + i * 512; pa.o2[1] = v2b;
    proj_kernel<<<1200, 256, 0, stream>>>(pa);
    attn_kernel<<<dim3(13, 8, 8), 256, 0, stream>>>(aa);
  }

  float* out = (float*)d_out;
  head_kernel<<<dim3(13, 4, 8), 256, 0, stream>>>(
      wb + 18 * WMAT, wb + 19 * WMAT, t1b, t2b,
      out1_b, out2_b, bn1_g, bn1_b, bn2_g, bn2_b, out);
}

// Round 4
// 487.416 us; speedup vs baseline: 2.7998x; 1.0774x over previous
//
#include <hip/hip_runtime.h>

typedef __bf16 bf16_t;
typedef __bf16 bf16x8 __attribute__((ext_vector_type(8)));
typedef __bf16 bf16x4 __attribute__((ext_vector_type(4)));
typedef float f32x4 __attribute__((ext_vector_type(4)));
typedef float f32x16 __attribute__((ext_vector_type(16)));
typedef unsigned u32x4 __attribute__((ext_vector_type(4)));

#define NTOK 1568
#define CDIM 512
#define BATCH 4
#define MROWS (BATCH*NTOK)  // 6272
#define RSQ1PEPS 0.9999950000374997f
#define CEXP 0.1803368801111204f   // 0.125 * log2(e)
#define DEFER_THR 44.3614195558365f // 8 / CEXP

__device__ __forceinline__ float fexp2(float x) {
  float r;
  asm("v_exp_f32 %0, %1" : "=v"(r) : "v"(x));
  return r;
}

// ---------------- cast all weights f32 -> bf16 (one launch) ----------------
struct CastArgs { const float* s[20]; };
__global__ __launch_bounds__(256) void cast_kernel(CastArgs ca, bf16_t* __restrict__ out) {
  int idx = blockIdx.x * 256 + threadIdx.x;   // float4 index over 20*65536
  int m = idx >> 16;
  const float4* sp = (const float4*)ca.s[m];
  float4 v = sp[idx & 65535];
  bf16x4 o;
  o[0] = (bf16_t)v.x; o[1] = (bf16_t)v.y; o[2] = (bf16_t)v.z; o[3] = (bf16_t)v.w;
  *(bf16x4*)(out + (size_t)idx * 4) = o;
}

// ---------------- tokenize both inputs: x[b][c][s] -> t[b][s][c] ----------------
struct TokArgs { const float* x[2]; float* tf[2]; bf16_t* tb[2]; };
__global__ __launch_bounds__(256) void tok_kernel(TokArgs ta) {
  __shared__ float tile[32][33];
  int z = blockIdx.z, sel = z >> 2, b = z & 3;
  int c0 = blockIdx.y * 32, s0 = blockIdx.x * 32;
  int tx = threadIdx.x, ty = threadIdx.y;   // (32, 8)
  const float* xp = ta.x[sel] + (size_t)b * CDIM * NTOK;
  for (int r = 0; r < 32; r += 8)
    tile[ty + r][tx] = xp[(size_t)(c0 + ty + r) * NTOK + s0 + tx];
  __syncthreads();
  float* tfp = ta.tf[sel] + (size_t)b * NTOK * CDIM;
  bf16_t* tbp = ta.tb[sel] + (size_t)b * NTOK * CDIM;
  for (int r = 0; r < 32; r += 8) {
    float v = tile[tx][ty + r];
    size_t idx = (size_t)(s0 + ty + r) * CDIM + c0 + tx;
    tfp[idx] = v;
    tbp[idx] = (bf16_t)v;
  }
}

// ---------------- LayerNorm both streams: f32 in -> bf16 out ----------------
__global__ __launch_bounds__(64) void ln_kernel(
    const float* __restrict__ t1, const float* __restrict__ t2,
    const float* __restrict__ g1, const float* __restrict__ b1,
    const float* __restrict__ g2, const float* __restrict__ b2,
    bf16_t* __restrict__ o1, bf16_t* __restrict__ o2) {
  int row = blockIdx.x;
  const float* t; const float* g; const float* bt; bf16_t* out;
  if (row < MROWS) { t = t1; g = g1; bt = b1; out = o1; }
  else { row -= MROWS; t = t2; g = g2; bt = b2; out = o2; }
  int l = threadIdx.x;  // 64
  const float* x = t + (size_t)row * CDIM;
  float4 v0 = ((const float4*)x)[l];
  float4 v1 = ((const float4*)x)[l + 64];
  float s = v0.x + v0.y + v0.z + v0.w + v1.x + v1.y + v1.z + v1.w;
  float sq = v0.x*v0.x + v0.y*v0.y + v0.z*v0.z + v0.w*v0.w
           + v1.x*v1.x + v1.y*v1.y + v1.z*v1.z + v1.w*v1.w;
  for (int m = 1; m < 64; m <<= 1) { s += __shfl_xor(s, m); sq += __shfl_xor(sq, m); }
  float mean = s * (1.f / 512.f);
  float var = sq * (1.f / 512.f) - mean * mean;
  float rs = rsqrtf(var + 1e-5f);
  float4 g0 = ((const float4*)g)[l], g1v = ((const float4*)g)[l + 64];
  float4 b0 = ((const float4*)bt)[l], b1v = ((const float4*)bt)[l + 64];
  bf16x4 o0, o1v;
  o0[0] = (bf16_t)((v0.x - mean) * rs * g0.x + b0.x);
  o0[1] = (bf16_t)((v0.y - mean) * rs * g0.y + b0.y);
  o0[2] = (bf16_t)((v0.z - mean) * rs * g0.z + b0.z);
  o0[3] = (bf16_t)((v0.w - mean) * rs * g0.w + b0.w);
  o1v[0] = (bf16_t)((v1.x - mean) * rs * g1v.x + b1v.x);
  o1v[1] = (bf16_t)((v1.y - mean) * rs * g1v.y + b1v.y);
  o1v[2] = (bf16_t)((v1.z - mean) * rs * g1v.z + b1v.z);
  o1v[3] = (bf16_t)((v1.w - mean) * rs * g1v.w + b1v.w);
  *(bf16x4*)(out + (size_t)row * CDIM + l * 4) = o0;
  *(bf16x4*)(out + (size_t)row * CDIM + 256 + l * 4) = o1v;
}

// ---------------- shared GEMM core: D = A[M][512] * B[N][512]^T ----------------
template<int MODE>
__device__ __forceinline__ void gemm_core(
    bf16_t (* __restrict__ As)[40], bf16_t (* __restrict__ Bs)[40],
    const bf16_t* __restrict__ A, const bf16_t* __restrict__ Bp,
    const float* __restrict__ bias, const float* __restrict__ bng,
    const float* __restrict__ bnb, bf16_t* __restrict__ outb,
    float* __restrict__ outf, int m0, int n0, int Nvalid) {
  int tid = threadIdx.x;
  int w = tid >> 6, l = tid & 63, lr = l & 15, kg = l >> 4;
  int wm = (w >> 1) * 64, wn = (w & 1) * 64;
  f32x4 acc[4][4];
  for (int i = 0; i < 4; i++)
    for (int j = 0; j < 4; j++)
      acc[i][j] = f32x4{0.f, 0.f, 0.f, 0.f};
  int srow = tid >> 1;
  int soff = (tid & 1) * 16;
  int brow = n0 + srow;
  if (MODE != 0 && brow >= Nvalid) brow = Nvalid - 1;
  const bf16_t* aq = A + (size_t)(m0 + srow) * CDIM + soff;
  const bf16_t* bq = Bp + (size_t)brow * CDIM + soff;
  for (int kk = 0; kk < 16; kk++) {
    __syncthreads();
    bf16x8 a0 = *(const bf16x8*)(aq);
    bf16x8 a1 = *(const bf16x8*)(aq + 8);
    bf16x8 b0 = *(const bf16x8*)(bq);
    bf16x8 b1 = *(const bf16x8*)(bq + 8);
    aq += 32; bq += 32;
    *(bf16x8*)&As[srow][soff] = a0;
    *(bf16x8*)&As[srow][soff + 8] = a1;
    *(bf16x8*)&Bs[srow][soff] = b0;
    *(bf16x8*)&Bs[srow][soff + 8] = b1;
    __syncthreads();
    bf16x8 af[4], bfr[4];
    for (int i = 0; i < 4; i++) af[i] = *(const bf16x8*)&As[wm + i * 16 + lr][kg * 8];
    for (int j = 0; j < 4; j++) bfr[j] = *(const bf16x8*)&Bs[wn + j * 16 + lr][kg * 8];
    for (int i = 0; i < 4; i++)
      for (int j = 0; j < 4; j++)
        acc[i][j] = __builtin_amdgcn_mfma_f32_16x16x32_bf16(af[i], bfr[j], acc[i][j], 0, 0, 0);
  }
  for (int i = 0; i < 4; i++)
    for (int j = 0; j < 4; j++) {
      int rbase = m0 + wm + i * 16 + kg * 4;
      int col = n0 + wn + j * 16 + lr;
      for (int r = 0; r < 4; r++) {
        int row = rbase + r;
        float v = acc[i][j][r];
        if (MODE == 0) {
          v += bias[col];
          outb[(size_t)row * CDIM + col] = (bf16_t)v;
        } else if (MODE == 1) {
          v += bias[row];
          v = v > 0.f ? v : 0.f;
          v *= RSQ1PEPS;
          v = v * bng[row] + bnb[row];
          if (col < Nvalid) outf[(size_t)row * NTOK + col] = v;
        } else {
          v += bias[row];
          if (col < Nvalid) outb[(size_t)row * NTOK + col] = (bf16_t)v;
        }
      }
    }
}

// ---------------- fused per-stage projections ----------------
struct ProjArgs {
  const bf16_t* A0[4]; const bf16_t* W0[4]; const float* b0[4]; bf16_t* o0[4];
  const bf16_t* W2[2]; const bf16_t* B2[2]; const float* b2[2]; bf16_t* o2[2];
};
__global__ __launch_bounds__(256) void proj_kernel(ProjArgs p) {
  __shared__ bf16_t As[128][40];
  __shared__ bf16_t Bs[128][40];
  int id = blockIdx.x;
  if (id < 784) {
    int set = id / 196, rem = id % 196;
    int n0 = (rem & 3) * 128, m0 = (rem >> 2) * 128;
    gemm_core<0>(As, Bs, p.A0[set], p.W0[set], p.b0[set], nullptr, nullptr,
                 p.o0[set], nullptr, m0, n0, 512);
  } else {
    int j = id - 784;
    int unit = j / 52;             // 0..7
    int which = unit >> 2, bat = unit & 3;
    int rem = j % 52;
    int n0 = (rem % 13) * 128, m0 = (rem / 13) * 128;
    gemm_core<2>(As, Bs, p.W2[which], p.B2[which] + (size_t)bat * NTOK * CDIM,
                 p.b2[which], nullptr, nullptr,
                 p.o2[which] + (size_t)bat * CDIM * NTOK, nullptr, m0, n0, NTOK);
  }
}

// ---------------- fused out-heads (MODE 1) ----------------
__global__ __launch_bounds__(256) void head_kernel(
    const bf16_t* __restrict__ W1, const bf16_t* __restrict__ W2,
    const bf16_t* __restrict__ t1b, const bf16_t* __restrict__ t2b,
    const float* __restrict__ b1, const float* __restrict__ b2,
    const float* __restrict__ bng1, const float* __restrict__ bnb1,
    const float* __restrict__ bng2, const float* __restrict__ bnb2,
    float* __restrict__ out) {
  __shared__ bf16_t As[128][40];
  __shared__ bf16_t Bs[128][40];
  int z = blockIdx.z;
  int which = z >> 2, bat = z & 3;
  const bf16_t* A = which ? W2 : W1;
  const bf16_t* Bp = (which ? t2b : t1b) + (size_t)bat * NTOK * CDIM;
  const float* bias = which ? b2 : b1;
  const float* bng = which ? bng2 : bng1;
  const float* bnb = which ? bnb2 : bnb1;
  float* outf = out + (size_t)which * BATCH * CDIM * NTOK + (size_t)bat * CDIM * NTOK;
  int m0 = blockIdx.y * 128, n0 = blockIdx.x * 128;
  gemm_core<1>(As, Bs, A, Bp, bias, bng, bnb, nullptr, outf, m0, n0, NTOK);
}

// ---------------- attention tile compute (32 keys) ----------------
__device__ __forceinline__ void attn_tile(
    const bf16_t* __restrict__ Ksl, const bf16_t* __restrict__ Vsl,
    const bf16x8* __restrict__ qf, int lo, int hi,
    float& m_i, float& l_i, f32x16& ot0, f32x16& ot1) {
  f32x16 st;
#pragma unroll
  for (int r = 0; r < 16; r++) st[r] = 0.f;
  __builtin_amdgcn_s_setprio(1);
#pragma unroll
  for (int c = 0; c < 4; c++) {
    bf16x8 kf = *(const bf16x8*)(Ksl + lo * 64 + ((c * 16 + hi * 8) ^ ((lo & 7) << 3)));
    st = __builtin_amdgcn_mfma_f32_32x32x16_bf16(kf, qf[c], st, 0, 0, 0);
  }
  __builtin_amdgcn_s_setprio(0);
  // pairwise max tree (depth 4)
  float a0 = fmaxf(st[0], st[1]), a1 = fmaxf(st[2], st[3]);
  float a2 = fmaxf(st[4], st[5]), a3 = fmaxf(st[6], st[7]);
  float a4 = fmaxf(st[8], st[9]), a5 = fmaxf(st[10], st[11]);
  float a6 = fmaxf(st[12], st[13]), a7 = fmaxf(st[14], st[15]);
  a0 = fmaxf(a0, a1); a2 = fmaxf(a2, a3); a4 = fmaxf(a4, a5); a6 = fmaxf(a6, a7);
  a0 = fmaxf(a0, a2); a4 = fmaxf(a4, a6);
  float tm = fmaxf(a0, a4);
  tm = fmaxf(tm, __shfl_xor(tm, 32));
  if (!__all(tm <= m_i + DEFER_THR)) {
    float mn = fmaxf(m_i, tm);
    float alpha = fexp2((m_i - mn) * CEXP);
#pragma unroll
    for (int r = 0; r < 16; r++) { ot0[r] *= alpha; ot1[r] *= alpha; }
    l_i *= alpha;
    m_i = mn;
  }
  float nmC = -m_i * CEXP;
  float p[16];
#pragma unroll
  for (int r = 0; r < 16; r++) p[r] = fexp2(fmaf(st[r], CEXP, nmC));
  // pairwise sum tree
  float s0 = (p[0] + p[1]) + (p[2] + p[3]);
  float s1 = (p[4] + p[5]) + (p[6] + p[7]);
  float s2 = (p[8] + p[9]) + (p[10] + p[11]);
  float s3 = (p[12] + p[13]) + (p[14] + p[15]);
  float ts = (s0 + s1) + (s2 + s3);
  ts += __shfl_xor(ts, 32);
  l_i += ts;
  // pack P to bf16 pairs, exchange halves with partner lane (l^32)
  unsigned pk[8];
#pragma unroll
  for (int g = 0; g < 8; g++) {
    union { bf16_t hh[2]; unsigned u; } cv;
    cv.hh[0] = (bf16_t)p[2 * g];
    cv.hh[1] = (bf16_t)p[2 * g + 1];
    pk[g] = cv.u;
  }
  unsigned x0 = __shfl_xor((int)pk[0], 32), x1 = __shfl_xor((int)pk[1], 32);
  unsigned x2 = __shfl_xor((int)pk[2], 32), x3 = __shfl_xor((int)pk[3], 32);
  unsigned x4 = __shfl_xor((int)pk[4], 32), x5 = __shfl_xor((int)pk[5], 32);
  unsigned x6 = __shfl_xor((int)pk[6], 32), x7 = __shfl_xor((int)pk[7], 32);
  union { u32x4 u; bf16x8 bv; } F0, F1;
  F0.u[0] = hi ? x2 : pk[0];
  F0.u[1] = hi ? x3 : pk[1];
  F0.u[2] = hi ? pk[2] : x0;
  F0.u[3] = hi ? pk[3] : x1;
  F1.u[0] = hi ? x6 : pk[4];
  F1.u[1] = hi ? x7 : pk[5];
  F1.u[2] = hi ? pk[6] : x4;
  F1.u[3] = hi ? pk[7] : x5;
  __builtin_amdgcn_s_setprio(1);
  {
    bf16x8 v0 = *(const bf16x8*)(Vsl + lo * 40 + hi * 8);
    ot0 = __builtin_amdgcn_mfma_f32_32x32x16_bf16(v0, F0.bv, ot0, 0, 0, 0);
    bf16x8 v1 = *(const bf16x8*)(Vsl + lo * 40 + 16 + hi * 8);
    ot0 = __builtin_amdgcn_mfma_f32_32x32x16_bf16(v1, F1.bv, ot0, 0, 0, 0);
    bf16x8 v2 = *(const bf16x8*)(Vsl + (32 + lo) * 40 + hi * 8);
    ot1 = __builtin_amdgcn_mfma_f32_32x32x16_bf16(v2, F0.bv, ot1, 0, 0, 0);
    bf16x8 v3 = *(const bf16x8*)(Vsl + (32 + lo) * 40 + 16 + hi * 8);
    ot1 = __builtin_amdgcn_mfma_f32_32x32x16_bf16(v3, F1.bv, ot1, 0, 0, 0);
  }
  __builtin_amdgcn_s_setprio(0);
}

// ---------------- fused attention: counted-vmcnt ring-4 pipeline + XCD swizzle ----------------
struct AttnArgs {
  const bf16_t* q[2]; const bf16_t* k[2]; const bf16_t* v[2];
  float* tf[2]; bf16_t* tb[2];
};

#define ATTN_STEP(TT, CUR, WSLOT, ISLOT, VLOAD, VSTORE)                              \
  {                                                                                  \
    int ktn = (TT) + 2 > 48 ? 48 : (TT) + 2;                                         \
    __builtin_amdgcn_global_load_lds(                                                \
        (const __attribute__((address_space(1))) unsigned*)(kgl + (size_t)ktn * 32 * CDIM), \
        (__attribute__((address_space(3))) unsigned*)&Ks[ISLOT][w * 8][0], 16, 0, 0); \
    VLOAD = *(const bf16x8*)(vgl + ktn * 32);                                        \
    attn_tile(&Ks[CUR][0][0], &Vs[CUR][0][0], qf, lo, hi, m_i, l_i, ot0, ot1);       \
    asm volatile("s_waitcnt vmcnt(2)" ::: "memory");                                 \
    *(bf16x8*)&Vs[WSLOT][vd][vc] = VSTORE;                                           \
    asm volatile("s_waitcnt lgkmcnt(0)\n\ts_barrier" ::: "memory");                  \
  }

__global__ __launch_bounds__(256) void attn_kernel(AttnArgs aa) {
  __shared__ alignas(16) bf16_t Ks[4][32][64];   // XOR-swizzled by ((row&7)<<3) elems
  __shared__ alignas(16) bf16_t Vs[4][64][40];   // V^T tile [d][k], stride 80B
  // XCD-aware decode: all 13 q-tiles of one (s,b,h) on one XCD
  int id = blockIdx.x;
  int xcd = id & 7, sl = id >> 3;          // sl in 0..103
  int g = xcd + ((sl / 13) << 3);          // group 0..63
  int qt = sl % 13;
  int ss = g >> 5, b = (g >> 3) & 3, h = g & 7;
  const bf16_t* qg = aa.q[ss];
  const bf16_t* kgp = aa.k[ss];
  const bf16_t* vtg = aa.v[ss];
  float* tf = aa.tf[ss];
  bf16_t* tb = aa.tb[ss];
  int tid = threadIdx.x, w = tid >> 6, l = tid & 63;
  int lo = l & 31, hi = l >> 5;
  const size_t kbase = ((size_t)b * NTOK) * CDIM + h * 64;
  const size_t vbase = ((size_t)b * CDIM + h * 64) * NTOK;

  int q0 = qt * 128 + w * 32;
  int qrow = q0 + lo;
  int qr = qrow < NTOK ? qrow : NTOK - 1;
  const bf16_t* qp = qg + kbase + (size_t)qr * CDIM + hi * 8;
  bf16x8 qf[4];
  qf[0] = *(const bf16x8*)(qp);
  qf[1] = *(const bf16x8*)(qp + 16);
  qf[2] = *(const bf16x8*)(qp + 32);
  qf[3] = *(const bf16x8*)(qp + 48);
  // force Q loads resolved so manual vmcnt counting below is exact
  asm volatile("" : "+v"(qf[0]), "+v"(qf[1]), "+v"(qf[2]), "+v"(qf[3]));
  asm volatile("s_waitcnt vmcnt(0)" ::: "memory");

  int ksr = w * 8 + (l >> 3);
  int ksc = 8 * ((l & 7) ^ ((l >> 3) & 7));
  const bf16_t* kgl = kgp + kbase + (size_t)ksr * CDIM + ksc;
  int vd = tid >> 2, vc = (tid & 3) * 8;
  const bf16_t* vgl = vtg + vbase + (size_t)vd * NTOK + vc;

  float m_i = -3.0e38f, l_i = 0.f;
  f32x16 ot0, ot1;
#pragma unroll
  for (int r = 0; r < 16; r++) { ot0[r] = 0.f; ot1[r] = 0.f; }

  // prologue: stage pairs for tiles 0 and 1 (K->LDS direct, V->regs)
  bf16x8 vrA, vrB;
  __builtin_amdgcn_global_load_lds(
      (const __attribute__((address_space(1))) unsigned*)(kgl),
      (__attribute__((address_space(3))) unsigned*)&Ks[0][w * 8][0], 16, 0, 0);
  vrB = *(const bf16x8*)(vgl);
  __builtin_amdgcn_global_load_lds(
      (const __attribute__((address_space(1))) unsigned*)(kgl + (size_t)32 * CDIM),
      (__attribute__((address_space(3))) unsigned*)&Ks[1][w * 8][0], 16, 0, 0);
  vrA = *(const bf16x8*)(vgl + 32);
  asm volatile("s_waitcnt vmcnt(2)" ::: "memory");
  *(bf16x8*)&Vs[0][vd][vc] = vrB;
  asm volatile("s_waitcnt lgkmcnt(0)\n\ts_barrier" ::: "memory");

  // main loop: tiles 0..47, ring-4 slots, depth-2 prefetch, counted vmcnt
  for (int t = 0; t < 48; t += 4) {
    ATTN_STEP(t + 0, 0, 1, 2, vrB, vrA);
    ATTN_STEP(t + 1, 1, 2, 3, vrA, vrB);
    ATTN_STEP(t + 2, 2, 3, 0, vrB, vrA);
    ATTN_STEP(t + 3, 3, 0, 1, vrA, vrB);
  }
  // tail: tile 48 (slot 0)
  attn_tile(&Ks[0][0][0], &Vs[0][0][0], qf, lo, hi, m_i, l_i, ot0, ot1);
  asm volatile("s_waitcnt vmcnt(0)" ::: "memory");  // drain dup prefetch before LDS retire

  if (qrow < NTOK) {
    float inv = 1.f / l_i;
    float* tfp = tf + ((size_t)b * NTOK + qrow) * CDIM + h * 64 + hi * 4;
    bf16_t* tbp = tb + ((size_t)b * NTOK + qrow) * CDIM + h * 64 + hi * 4;
#pragma unroll
    for (int db = 0; db < 2; db++) {
#pragma unroll
      for (int gq = 0; gq < 4; gq++) {
        int doff = db * 32 + gq * 8;
        float4 old = *(float4*)(tfp + doff);
        float4 nv;
        float a0 = (db ? ot1[gq * 4 + 0] : ot0[gq * 4 + 0]) * inv;
        float a1 = (db ? ot1[gq * 4 + 1] : ot0[gq * 4 + 1]) * inv;
        float a2 = (db ? ot1[gq * 4 + 2] : ot0[gq * 4 + 2]) * inv;
        float a3 = (db ? ot1[gq * 4 + 3] : ot0[gq * 4 + 3]) * inv;
        nv.x = old.x + a0; nv.y = old.y + a1; nv.z = old.z + a2; nv.w = old.w + a3;
        *(float4*)(tfp + doff) = nv;
        bf16x4 ob;
        ob[0] = (bf16_t)nv.x; ob[1] = (bf16_t)nv.y;
        ob[2] = (bf16_t)nv.z; ob[3] = (bf16_t)nv.w;
        *(bf16x4*)(tbp + doff) = ob;
      }
    }
  }
}

extern "C" void kernel_launch(void* const* d_in, const int* in_sizes, int n_in,
                              void* d_out, int out_size, void* d_ws, size_t ws_size,
                              hipStream_t stream) {
  (void)in_sizes; (void)n_in; (void)out_size; (void)ws_size;
  const float* x1 = (const float*)d_in[0];
  const float* x2 = (const float*)d_in[1];
  const float* Wq1 = (const float*)d_in[2];
  const float* bq1 = (const float*)d_in[3];
  const float* Wk1 = (const float*)d_in[4];
  const float* bk1 = (const float*)d_in[5];
  const float* Wv1 = (const float*)d_in[6];
  const float* bv1 = (const float*)d_in[7];
  const float* ln1_g = (const float*)d_in[8];
  const float* ln1_b = (const float*)d_in[9];
  const float* Wq2 = (const float*)d_in[10];
  const float* bq2 = (const float*)d_in[11];
  const float* Wk2 = (const float*)d_in[12];
  const float* bk2 = (const float*)d_in[13];
  const float* Wv2 = (const float*)d_in[14];
  const float* bv2 = (const float*)d_in[15];
  const float* ln2_g = (const float*)d_in[16];
  const float* ln2_b = (const float*)d_in[17];
  const float* out1_w = (const float*)d_in[18];
  const float* out1_b = (const float*)d_in[19];
  const float* bn1_g = (const float*)d_in[20];
  const float* bn1_b = (const float*)d_in[21];
  const float* out2_w = (const float*)d_in[22];
  const float* out2_b = (const float*)d_in[23];
  const float* bn2_g = (const float*)d_in[24];
  const float* bn2_b = (const float*)d_in[25];

  const size_t WMAT = 512 * 512;
  char* ws = (char*)d_ws;
  bf16_t* wb = (bf16_t*)ws;
  size_t off = 20 * WMAT * sizeof(bf16_t);
  float* t1f = (float*)(ws + off); off += (size_t)MROWS * CDIM * 4;
  float* t2f = (float*)(ws + off); off += (size_t)MROWS * CDIM * 4;
  bf16_t* t1b = (bf16_t*)(ws + off); off += (size_t)MROWS * CDIM * 2;
  bf16_t* t2b = (bf16_t*)(ws + off); off += (size_t)MROWS * CDIM * 2;
  bf16_t* l1b = (bf16_t*)(ws + off); off += (size_t)MROWS * CDIM * 2;
  bf16_t* l2b = (bf16_t*)(ws + off); off += (size_t)MROWS * CDIM * 2;
  bf16_t* q1b = (bf16_t*)(ws + off); off += (size_t)MROWS * CDIM * 2;
  bf16_t* k1b = (bf16_t*)(ws + off); off += (size_t)MROWS * CDIM * 2;
  bf16_t* v1b = (bf16_t*)(ws + off); off += (size_t)MROWS * CDIM * 2;  // V^T [b][512][1568]
  bf16_t* q2b = (bf16_t*)(ws + off); off += (size_t)MROWS * CDIM * 2;
  bf16_t* k2b = (bf16_t*)(ws + off); off += (size_t)MROWS * CDIM * 2;
  bf16_t* v2b = (bf16_t*)(ws + off); off += (size_t)MROWS * CDIM * 2;  // V^T

  CastArgs ca;
  for (int i = 0; i < 3; i++) {
    ca.s[0 + i] = Wq1 + (size_t)i * WMAT;
    ca.s[3 + i] = Wk1 + (size_t)i * WMAT;
    ca.s[6 + i] = Wv1 + (size_t)i * WMAT;
    ca.s[9 + i] = Wq2 + (size_t)i * WMAT;
    ca.s[12 + i] = Wk2 + (size_t)i * WMAT;
    ca.s[15 + i] = Wv2 + (size_t)i * WMAT;
  }
  ca.s[18] = out1_w;
  ca.s[19] = out2_w;
  cast_kernel<<<5120, 256, 0, stream>>>(ca, wb);

  TokArgs ta;
  ta.x[0] = x1; ta.x[1] = x2;
  ta.tf[0] = t1f; ta.tf[1] = t2f;
  ta.tb[0] = t1b; ta.tb[1] = t2b;
  tok_kernel<<<dim3(49, 16, 8), dim3(32, 8), 0, stream>>>(ta);

  AttnArgs aa;
  aa.q[0] = q1b; aa.q[1] = q2b;
  aa.k[0] = k1b; aa.k[1] = k2b;
  aa.v[0] = v1b; aa.v[1] = v2b;
  aa.tf[0] = t1f; aa.tf[1] = t2f;
  aa.tb[0] = t1b; aa.tb[1] = t2b;

  for (int i = 0; i < 3; i++) {
    ln_kernel<<<2 * MROWS, 64, 0, stream>>>(t1f, t2f,
        ln1_g + i * 512, ln1_b + i * 512, ln2_g + i * 512, ln2_b + i * 512,
        l1b, l2b);
    ProjArgs pa;
    pa.A0[0] = l1b; pa.W0[0] = wb + (0 + i) * WMAT; pa.b0[0] = bq1 + i * 512; pa.o0[0] = q1b;
    pa.A0[1] = t2b; pa.W0[1] = wb + (3 + i) * WMAT; pa.b0[1] = bk1 + i * 512; pa.o0[1] = k1b;
    pa.A0[2] = l2b; pa.W0[2] = wb + (9 + i) * WMAT; pa.b0[2] = bq2 + i * 512; pa.o0[2] = q2b;
    pa.A0[3] = t1b; pa.W0[3] = wb + (12 + i) * WMAT; pa.b0[3] = bk2 + i * 512; pa.o0[3] = k2b;
    pa.W2[0] = wb + (6 + i) * WMAT; pa.B2[0] = t2b; pa.b2[0] = bv1 + i * 512; pa.o2[0] = v1b;
    pa.W2[1] = wb + (15 + i) * WMAT; pa.B2[1] = t1b; pa.b2[1] = bv2 + i * 512; pa.o2[1] = v2b;
    proj_kernel<<<1200, 256, 0, stream>>>(pa);
    attn_kernel<<<832, 256, 0, stream>>>(aa);
  }

  float* out = (float*)d_out;
  head_kernel<<<dim3(13, 4, 8), 256, 0, stream>>>(
      wb + 18 * WMAT, wb + 19 * WMAT, t1b, t2b,
      out1_b, out2_b, bn1_g, bn1_b, bn2_g, bn2_b, out);
}

// Round 6
// 452.272 us; speedup vs baseline: 3.0174x; 1.0777x over previous
//
#include <hip/hip_runtime.h>

typedef __bf16 bf16_t;
typedef __bf16 bf16x8 __attribute__((ext_vector_type(8)));
typedef __bf16 bf16x4 __attribute__((ext_vector_type(4)));
typedef float f32x4 __attribute__((ext_vector_type(4)));
typedef float f32x16 __attribute__((ext_vector_type(16)));
typedef unsigned u32x4 __attribute__((ext_vector_type(4)));

#define NTOK 1568
#define CDIM 512
#define BATCH 4
#define MROWS (BATCH*NTOK)  // 6272
#define RSQ1PEPS 0.9999950000374997f
#define CEXP 0.1803368801111204f    // 0.125 * log2(e)
#define DEFER_THR 44.3614195558365f // 8 / CEXP

__device__ __forceinline__ float fexp2(float x) {
  float r;
  asm("v_exp_f32 %0, %1" : "=v"(r) : "v"(x));
  return r;
}

__device__ __forceinline__ void glds16(const bf16_t* src, bf16_t* dst) {
  __builtin_amdgcn_global_load_lds(
      (const __attribute__((address_space(1))) unsigned*)src,
      (__attribute__((address_space(3))) unsigned*)dst, 16, 0, 0);
}

// ---------------- cast all weights f32 -> bf16 (one launch) ----------------
struct CastArgs { const float* s[20]; };
__global__ __launch_bounds__(256) void cast_kernel(CastArgs ca, bf16_t* __restrict__ out) {
  int idx = blockIdx.x * 256 + threadIdx.x;   // float4 index over 20*65536
  int m = idx >> 16;
  const float4* sp = (const float4*)ca.s[m];
  float4 v = sp[idx & 65535];
  bf16x4 o;
  o[0] = (bf16_t)v.x; o[1] = (bf16_t)v.y; o[2] = (bf16_t)v.z; o[3] = (bf16_t)v.w;
  *(bf16x4*)(out + (size_t)idx * 4) = o;
}

// ---------------- tokenize both inputs: x[b][c][s] -> t[b][s][c] ----------------
struct TokArgs { const float* x[2]; float* tf[2]; bf16_t* tb[2]; };
__global__ __launch_bounds__(256) void tok_kernel(TokArgs ta) {
  __shared__ float tile[32][33];
  int z = blockIdx.z, sel = z >> 2, b = z & 3;
  int c0 = blockIdx.y * 32, s0 = blockIdx.x * 32;
  int tx = threadIdx.x, ty = threadIdx.y;   // (32, 8)
  const float* xp = ta.x[sel] + (size_t)b * CDIM * NTOK;
  for (int r = 0; r < 32; r += 8)
    tile[ty + r][tx] = xp[(size_t)(c0 + ty + r) * NTOK + s0 + tx];
  __syncthreads();
  float* tfp = ta.tf[sel] + (size_t)b * NTOK * CDIM;
  bf16_t* tbp = ta.tb[sel] + (size_t)b * NTOK * CDIM;
  for (int r = 0; r < 32; r += 8) {
    float v = tile[tx][ty + r];
    size_t idx = (size_t)(s0 + ty + r) * CDIM + c0 + tx;
    tfp[idx] = v;
    tbp[idx] = (bf16_t)v;
  }
}

// ---------------- LayerNorm both streams: f32 in -> bf16 out ----------------
__global__ __launch_bounds__(64) void ln_kernel(
    const float* __restrict__ t1, const float* __restrict__ t2,
    const float* __restrict__ g1, const float* __restrict__ b1,
    const float* __restrict__ g2, const float* __restrict__ b2,
    bf16_t* __restrict__ o1, bf16_t* __restrict__ o2) {
  int row = blockIdx.x;
  const float* t; const float* g; const float* bt; bf16_t* out;
  if (row < MROWS) { t = t1; g = g1; bt = b1; out = o1; }
  else { row -= MROWS; t = t2; g = g2; bt = b2; out = o2; }
  int l = threadIdx.x;  // 64
  const float* x = t + (size_t)row * CDIM;
  float4 v0 = ((const float4*)x)[l];
  float4 v1 = ((const float4*)x)[l + 64];
  float s = v0.x + v0.y + v0.z + v0.w + v1.x + v1.y + v1.z + v1.w;
  float sq = v0.x*v0.x + v0.y*v0.y + v0.z*v0.z + v0.w*v0.w
           + v1.x*v1.x + v1.y*v1.y + v1.z*v1.z + v1.w*v1.w;
  for (int m = 1; m < 64; m <<= 1) { s += __shfl_xor(s, m); sq += __shfl_xor(sq, m); }
  float mean = s * (1.f / 512.f);
  float var = sq * (1.f / 512.f) - mean * mean;
  float rs = rsqrtf(var + 1e-5f);
  float4 g0 = ((const float4*)g)[l], g1v = ((const float4*)g)[l + 64];
  float4 b0 = ((const float4*)bt)[l], b1v = ((const float4*)bt)[l + 64];
  bf16x4 o0, o1v;
  o0[0] = (bf16_t)((v0.x - mean) * rs * g0.x + b0.x);
  o0[1] = (bf16_t)((v0.y - mean) * rs * g0.y + b0.y);
  o0[2] = (bf16_t)((v0.z - mean) * rs * g0.z + b0.z);
  o0[3] = (bf16_t)((v0.w - mean) * rs * g0.w + b0.w);
  o1v[0] = (bf16_t)((v1.x - mean) * rs * g1v.x + b1v.x);
  o1v[1] = (bf16_t)((v1.y - mean) * rs * g1v.y + b1v.y);
  o1v[2] = (bf16_t)((v1.z - mean) * rs * g1v.z + b1v.z);
  o1v[3] = (bf16_t)((v1.w - mean) * rs * g1v.w + b1v.w);
  *(bf16x4*)(out + (size_t)row * CDIM + l * 4) = o0;
  *(bf16x4*)(out + (size_t)row * CDIM + 256 + l * 4) = o1v;
}

// ---------------- shared GEMM core: D = A[M][512] * B[N][512]^T ----------------
template<int MODE>
__device__ __forceinline__ void gemm_core(
    bf16_t (* __restrict__ As)[40], bf16_t (* __restrict__ Bs)[40],
    const bf16_t* __restrict__ A, const bf16_t* __restrict__ Bp,
    const float* __restrict__ bias, const float* __restrict__ bng,
    const float* __restrict__ bnb, bf16_t* __restrict__ outb,
    float* __restrict__ outf, int m0, int n0, int Nvalid) {
  int tid = threadIdx.x;
  int w = tid >> 6, l = tid & 63, lr = l & 15, kg = l >> 4;
  int wm = (w >> 1) * 64, wn = (w & 1) * 64;
  f32x4 acc[4][4];
  for (int i = 0; i < 4; i++)
    for (int j = 0; j < 4; j++)
      acc[i][j] = f32x4{0.f, 0.f, 0.f, 0.f};
  int srow = tid >> 1;
  int soff = (tid & 1) * 16;
  int brow = n0 + srow;
  if (MODE != 0 && brow >= Nvalid) brow = Nvalid - 1;
  const bf16_t* aq = A + (size_t)(m0 + srow) * CDIM + soff;
  const bf16_t* bq = Bp + (size_t)brow * CDIM + soff;
  for (int kk = 0; kk < 16; kk++) {
    __syncthreads();
    bf16x8 a0 = *(const bf16x8*)(aq);
    bf16x8 a1 = *(const bf16x8*)(aq + 8);
    bf16x8 b0 = *(const bf16x8*)(bq);
    bf16x8 b1 = *(const bf16x8*)(bq + 8);
    aq += 32; bq += 32;
    *(bf16x8*)&As[srow][soff] = a0;
    *(bf16x8*)&As[srow][soff + 8] = a1;
    *(bf16x8*)&Bs[srow][soff] = b0;
    *(bf16x8*)&Bs[srow][soff + 8] = b1;
    __syncthreads();
    bf16x8 af[4], bfr[4];
    for (int i = 0; i < 4; i++) af[i] = *(const bf16x8*)&As[wm + i * 16 + lr][kg * 8];
    for (int j = 0; j < 4; j++) bfr[j] = *(const bf16x8*)&Bs[wn + j * 16 + lr][kg * 8];
    for (int i = 0; i < 4; i++)
      for (int j = 0; j < 4; j++)
        acc[i][j] = __builtin_amdgcn_mfma_f32_16x16x32_bf16(af[i], bfr[j], acc[i][j], 0, 0, 0);
  }
  for (int i = 0; i < 4; i++)
    for (int j = 0; j < 4; j++) {
      int rbase = m0 + wm + i * 16 + kg * 4;
      int col = n0 + wn + j * 16 + lr;
      for (int r = 0; r < 4; r++) {
        int row = rbase + r;
        float v = acc[i][j][r];
        if (MODE == 0) {
          v += bias[col];
          outb[(size_t)row * CDIM + col] = (bf16_t)v;
        } else if (MODE == 1) {
          v += bias[row];
          v = v > 0.f ? v : 0.f;
          v *= RSQ1PEPS;
          v = v * bng[row] + bnb[row];
          if (col < Nvalid) outf[(size_t)row * NTOK + col] = v;
        } else {
          v += bias[row];
          if (col < Nvalid) outb[(size_t)row * NTOK + col] = (bf16_t)v;
        }
      }
    }
}

// ---------------- fused per-stage projections ----------------
struct ProjArgs {
  const bf16_t* A0[4]; const bf16_t* W0[4]; const float* b0[4]; bf16_t* o0[4];
  const bf16_t* W2[2]; const bf16_t* B2[2]; const float* b2[2]; bf16_t* o2[2];
};
__global__ __launch_bounds__(256) void proj_kernel(ProjArgs p) {
  __shared__ bf16_t As[128][40];
  __shared__ bf16_t Bs[128][40];
  int id = blockIdx.x;
  if (id < 784) {
    int set = id / 196, rem = id % 196;
    int n0 = (rem & 3) * 128, m0 = (rem >> 2) * 128;
    gemm_core<0>(As, Bs, p.A0[set], p.W0[set], p.b0[set], nullptr, nullptr,
                 p.o0[set], nullptr, m0, n0, 512);
  } else {
    int j = id - 784;
    int unit = j / 52;             // 0..7
    int which = unit >> 2, bat = unit & 3;
    int rem = j % 52;
    int n0 = (rem % 13) * 128, m0 = (rem / 13) * 128;
    gemm_core<2>(As, Bs, p.W2[which], p.B2[which] + (size_t)bat * NTOK * CDIM,
                 p.b2[which], nullptr, nullptr,
                 p.o2[which] + (size_t)bat * CDIM * NTOK, nullptr, m0, n0, NTOK);
  }
}

// ---------------- fused out-heads (MODE 1) ----------------
__global__ __launch_bounds__(256) void head_kernel(
    const bf16_t* __restrict__ W1, const bf16_t* __restrict__ W2,
    const bf16_t* __restrict__ t1b, const bf16_t* __restrict__ t2b,
    const float* __restrict__ b1, const float* __restrict__ b2,
    const float* __restrict__ bng1, const float* __restrict__ bnb1,
    const float* __restrict__ bng2, const float* __restrict__ bnb2,
    float* __restrict__ out) {
  __shared__ bf16_t As[128][40];
  __shared__ bf16_t Bs[128][40];
  int z = blockIdx.z;
  int which = z >> 2, bat = z & 3;
  const bf16_t* A = which ? W2 : W1;
  const bf16_t* Bp = (which ? t2b : t1b) + (size_t)bat * NTOK * CDIM;
  const float* bias = which ? b2 : b1;
  const float* bng = which ? bng2 : bng1;
  const float* bnb = which ? bnb2 : bnb1;
  float* outf = out + (size_t)which * BATCH * CDIM * NTOK + (size_t)bat * CDIM * NTOK;
  int m0 = blockIdx.y * 128, n0 = blockIdx.x * 128;
  gemm_core<1>(As, Bs, A, Bp, bias, bng, bnb, nullptr, outf, m0, n0, NTOK);
}

// ---------------- attention helpers ----------------
__device__ __forceinline__ float tree_max16(const f32x16& s) {
  float a0 = fmaxf(s[0], s[1]), a1 = fmaxf(s[2], s[3]);
  float a2 = fmaxf(s[4], s[5]), a3 = fmaxf(s[6], s[7]);
  float a4 = fmaxf(s[8], s[9]), a5 = fmaxf(s[10], s[11]);
  float a6 = fmaxf(s[12], s[13]), a7 = fmaxf(s[14], s[15]);
  a0 = fmaxf(a0, a1); a2 = fmaxf(a2, a3); a4 = fmaxf(a4, a5); a6 = fmaxf(a6, a7);
  return fmaxf(fmaxf(a0, a2), fmaxf(a4, a6));
}

// build two PV B-fragments (16 keys each) from 16 probabilities via permlane32_swap
__device__ __forceinline__ void build_frags(const float* p, bf16x8& Fa, bf16x8& Fb) {
  unsigned pk[8];
#pragma unroll
  for (int g = 0; g < 8; g++) {
    union { bf16_t hh[2]; unsigned u; } cv;
    cv.hh[0] = (bf16_t)p[2 * g];
    cv.hh[1] = (bf16_t)p[2 * g + 1];
    pk[g] = cv.u;
  }
  // permlane32_swap(x,y): x.hi <-> y.lo  => exactly the {own, partner} selection
  asm volatile("v_permlane32_swap_b32 %0, %1" : "+v"(pk[0]), "+v"(pk[2]));
  asm volatile("v_permlane32_swap_b32 %0, %1" : "+v"(pk[1]), "+v"(pk[3]));
  asm volatile("v_permlane32_swap_b32 %0, %1" : "+v"(pk[4]), "+v"(pk[6]));
  asm volatile("v_permlane32_swap_b32 %0, %1" : "+v"(pk[5]), "+v"(pk[7]));
  union { u32x4 u; bf16x8 bv; } A, B;
  A.u[0] = pk[0]; A.u[1] = pk[1]; A.u[2] = pk[2]; A.u[3] = pk[3];
  B.u[0] = pk[4]; B.u[1] = pk[5]; B.u[2] = pk[6]; B.u[3] = pk[7];
  Fa = A.bv; Fb = B.bv;
}

// one 64-key tile: S^T = K*Q (2x 32x32), softmax, O^T += V^T * P
template<bool TAIL>
__device__ __forceinline__ void attn_tile64(
    const bf16_t* __restrict__ Ksl, const bf16_t* __restrict__ Vsl,
    const bf16x8* __restrict__ qf, const f32x16& z, int lo, int hi,
    float& m_i, float& l_i, f32x16& ot0, f32x16& ot1) {
  int sw = (lo & 7) << 3;
  f32x16 sa, sb;
  __builtin_amdgcn_s_setprio(1);
  {
    const bf16_t* kr = Ksl + lo * 64;
    bf16x8 k0 = *(const bf16x8*)(kr + ((hi * 8) ^ sw));
    sa = __builtin_amdgcn_mfma_f32_32x32x16_bf16(k0, qf[0], z, 0, 0, 0);
    bf16x8 k1 = *(const bf16x8*)(kr + ((16 + hi * 8) ^ sw));
    sa = __builtin_amdgcn_mfma_f32_32x32x16_bf16(k1, qf[1], sa, 0, 0, 0);
    bf16x8 k2 = *(const bf16x8*)(kr + ((32 + hi * 8) ^ sw));
    sa = __builtin_amdgcn_mfma_f32_32x32x16_bf16(k2, qf[2], sa, 0, 0, 0);
    bf16x8 k3 = *(const bf16x8*)(kr + ((48 + hi * 8) ^ sw));
    sa = __builtin_amdgcn_mfma_f32_32x32x16_bf16(k3, qf[3], sa, 0, 0, 0);
  }
  if (!TAIL) {
    const bf16_t* kr = Ksl + (32 + lo) * 64;
    bf16x8 k0 = *(const bf16x8*)(kr + ((hi * 8) ^ sw));
    sb = __builtin_amdgcn_mfma_f32_32x32x16_bf16(k0, qf[0], z, 0, 0, 0);
    bf16x8 k1 = *(const bf16x8*)(kr + ((16 + hi * 8) ^ sw));
    sb = __builtin_amdgcn_mfma_f32_32x32x16_bf16(k1, qf[1], sb, 0, 0, 0);
    bf16x8 k2 = *(const bf16x8*)(kr + ((32 + hi * 8) ^ sw));
    sb = __builtin_amdgcn_mfma_f32_32x32x16_bf16(k2, qf[2], sb, 0, 0, 0);
    bf16x8 k3 = *(const bf16x8*)(kr + ((48 + hi * 8) ^ sw));
    sb = __builtin_amdgcn_mfma_f32_32x32x16_bf16(k3, qf[3], sb, 0, 0, 0);
  }
  __builtin_amdgcn_s_setprio(0);
  float tm = tree_max16(sa);
  if (!TAIL) tm = fmaxf(tm, tree_max16(sb));
  tm = fmaxf(tm, __shfl_xor(tm, 32));
  if (!__all(tm <= m_i + DEFER_THR)) {
    float mn = fmaxf(m_i, tm);
    float alpha = fexp2((m_i - mn) * CEXP);
#pragma unroll
    for (int r = 0; r < 16; r++) { ot0[r] *= alpha; ot1[r] *= alpha; }
    l_i *= alpha;
    m_i = mn;
  }
  float nmC = -m_i * CEXP;
  float pa[16], pb[16];
#pragma unroll
  for (int r = 0; r < 16; r++) pa[r] = fexp2(fmaf(sa[r], CEXP, nmC));
  float ts = ((pa[0] + pa[1]) + (pa[2] + pa[3])) + ((pa[4] + pa[5]) + (pa[6] + pa[7]))
           + ((pa[8] + pa[9]) + (pa[10] + pa[11])) + ((pa[12] + pa[13]) + (pa[14] + pa[15]));
  if (!TAIL) {
#pragma unroll
    for (int r = 0; r < 16; r++) pb[r] = fexp2(fmaf(sb[r], CEXP, nmC));
    ts += ((pb[0] + pb[1]) + (pb[2] + pb[3])) + ((pb[4] + pb[5]) + (pb[6] + pb[7]))
        + ((pb[8] + pb[9]) + (pb[10] + pb[11])) + ((pb[12] + pb[13]) + (pb[14] + pb[15]));
  }
  ts += __shfl_xor(ts, 32);
  l_i += ts;
  bf16x8 F0, F1, F2, F3;
  build_frags(pa, F0, F1);
  if (!TAIL) build_frags(pb, F2, F3);
  __builtin_amdgcn_s_setprio(1);
  {
    const bf16_t* vr = Vsl + lo * 64;
    bf16x8 v0 = *(const bf16x8*)(vr + ((hi * 8) ^ sw));
    ot0 = __builtin_amdgcn_mfma_f32_32x32x16_bf16(v0, F0, ot0, 0, 0, 0);
    bf16x8 v1 = *(const bf16x8*)(vr + ((16 + hi * 8) ^ sw));
    ot0 = __builtin_amdgcn_mfma_f32_32x32x16_bf16(v1, F1, ot0, 0, 0, 0);
    if (!TAIL) {
      bf16x8 v2 = *(const bf16x8*)(vr + ((32 + hi * 8) ^ sw));
      ot0 = __builtin_amdgcn_mfma_f32_32x32x16_bf16(v2, F2, ot0, 0, 0, 0);
      bf16x8 v3 = *(const bf16x8*)(vr + ((48 + hi * 8) ^ sw));
      ot0 = __builtin_amdgcn_mfma_f32_32x32x16_bf16(v3, F3, ot0, 0, 0, 0);
    }
  }
  {
    const bf16_t* vr = Vsl + (32 + lo) * 64;
    bf16x8 v0 = *(const bf16x8*)(vr + ((hi * 8) ^ sw));
    ot1 = __builtin_amdgcn_mfma_f32_32x32x16_bf16(v0, F0, ot1, 0, 0, 0);
    bf16x8 v1 = *(const bf16x8*)(vr + ((16 + hi * 8) ^ sw));
    ot1 = __builtin_amdgcn_mfma_f32_32x32x16_bf16(v1, F1, ot1, 0, 0, 0);
    if (!TAIL) {
      bf16x8 v2 = *(const bf16x8*)(vr + ((32 + hi * 8) ^ sw));
      ot1 = __builtin_amdgcn_mfma_f32_32x32x16_bf16(v2, F2, ot1, 0, 0, 0);
      bf16x8 v3 = *(const bf16x8*)(vr + ((48 + hi * 8) ^ sw));
      ot1 = __builtin_amdgcn_mfma_f32_32x32x16_bf16(v3, F3, ot1, 0, 0, 0);
    }
  }
  __builtin_amdgcn_s_setprio(0);
}

// ---------------- fused attention: KVB=64, ring-3, depth-2 prefetch, XCD swizzle ----------------
struct AttnArgs {
  const bf16_t* q[2]; const bf16_t* k[2]; const bf16_t* v[2];
  float* tf[2]; bf16_t* tb[2];
};

// stage tile TN (K and V, 4 glds per wave) into ring slot SL
// NOTE: internal var renamed tnS_ (R5 bug: STAGE(tn_,..) self-shadowed -> garbage address)
#define STAGE(TN, SL)                                                         \
  {                                                                           \
    int tnS_ = (TN);                                                          \
    const bf16_t* k0 = kgl + (size_t)tnS_ * (64 * CDIM);                      \
    const bf16_t* k1 = (tnS_ == 24) ? (kgl + (size_t)1536 * CDIM)             \
                                    : (k0 + (size_t)32 * CDIM);               \
    const bf16_t* v0 = (tnS_ == 24) ? vglT : (vgl + tnS_ * 64);               \
    glds16(k0, &Ks[SL][wq8][0]);                                              \
    glds16(k1, &Ks[SL][32 + wq8][0]);                                         \
    glds16(v0, &Vs[SL][wq8][0]);                                              \
    glds16(v0 + (size_t)32 * NTOK, &Vs[SL][32 + wq8][0]);                     \
  }

#define ATTN_STEP(TT, CUR, NXT)                                               \
  {                                                                           \
    int tn_ = (TT) + 2; if (tn_ > 24) tn_ = 24;                               \
    STAGE(tn_, NXT);                                                          \
    attn_tile64<false>(&Ks[CUR][0][0], &Vs[CUR][0][0], qf, z, lo, hi,         \
                       m_i, l_i, ot0, ot1);                                   \
    asm volatile("s_waitcnt vmcnt(4)" ::: "memory");                          \
    __builtin_amdgcn_s_barrier();                                             \
  }

__global__ __launch_bounds__(256) void attn_kernel(AttnArgs aa) {
  __shared__ alignas(16) bf16_t Ks[3][64][64];   // 24KB, XOR-swizzled cols
  __shared__ alignas(16) bf16_t Vs[3][64][64];   // 24KB, V^T, same swizzle
  // XCD-aware decode: all 13 q-tiles of one (s,b,h) on one XCD
  int id = blockIdx.x;
  int xcd = id & 7, sl = id >> 3;          // sl in 0..103
  int g = xcd + ((sl / 13) << 3);          // group 0..63
  int qt = sl % 13;
  int ss = g >> 5, b = (g >> 3) & 3, h = g & 7;
  const bf16_t* qg = aa.q[ss];
  const bf16_t* kgp = aa.k[ss];
  const bf16_t* vtg = aa.v[ss];
  float* tf = aa.tf[ss];
  bf16_t* tb = aa.tb[ss];
  int tid = threadIdx.x, w = tid >> 6, l = tid & 63;
  int lo = l & 31, hi = l >> 5;
  int wq8 = w * 8;
  const size_t kbase = ((size_t)b * NTOK) * CDIM + h * 64;
  const size_t vbase = ((size_t)b * CDIM + h * 64) * NTOK;

  int q0 = qt * 128 + w * 32;
  int qrow = q0 + lo;
  int qr = qrow < NTOK ? qrow : NTOK - 1;
  const bf16_t* qp = qg + kbase + (size_t)qr * CDIM + hi * 8;
  bf16x8 qf[4];
  qf[0] = *(const bf16x8*)(qp);
  qf[1] = *(const bf16x8*)(qp + 16);
  qf[2] = *(const bf16x8*)(qp + 32);
  qf[3] = *(const bf16x8*)(qp + 48);
  asm volatile("" : "+v"(qf[0]), "+v"(qf[1]), "+v"(qf[2]), "+v"(qf[3]));
  asm volatile("s_waitcnt vmcnt(0)" ::: "memory");   // drain Q so vmcnt counting is exact

  // per-lane staging source addresses (pre-swizzled cols, slot^(row&7))
  int row0 = wq8 + (l >> 3);
  int slotx = (l & 7) ^ ((l >> 3) & 7);
  const bf16_t* kgl = kgp + kbase + (size_t)row0 * CDIM + slotx * 8;
  const bf16_t* vgl = vtg + vbase + (size_t)row0 * NTOK + slotx * 8;
  int kcT = 1536 + slotx * 8; if (kcT > 1560) kcT = 1560;   // tail V col clamp
  const bf16_t* vglT = vtg + vbase + (size_t)row0 * NTOK + kcT;

  float m_i = -3.0e38f, l_i = 0.f;
  f32x16 ot0, ot1, z;
#pragma unroll
  for (int r = 0; r < 16; r++) { ot0[r] = 0.f; ot1[r] = 0.f; z[r] = 0.f; }

  // prologue: stage tiles 0 and 1
  STAGE(0, 0);
  STAGE(1, 1);
  asm volatile("s_waitcnt vmcnt(4)" ::: "memory");
  __builtin_amdgcn_s_barrier();

  // main loop: tiles 0..23, ring-3, depth-2 prefetch, counted vmcnt
  for (int t = 0; t < 24; t += 3) {
    ATTN_STEP(t + 0, 0, 2);
    ATTN_STEP(t + 1, 1, 0);
    ATTN_STEP(t + 2, 2, 1);
  }
  // tail: tile 24 (slot 0), keys 1536..1567 valid only
  attn_tile64<true>(&Ks[0][0][0], &Vs[0][0][0], qf, z, lo, hi, m_i, l_i, ot0, ot1);
  asm volatile("s_waitcnt vmcnt(0)" ::: "memory");   // drain dup prefetch

  if (qrow < NTOK) {
    float inv = 1.f / l_i;
    float* tfp = tf + ((size_t)b * NTOK + qrow) * CDIM + h * 64 + hi * 4;
    bf16_t* tbp = tb + ((size_t)b * NTOK + qrow) * CDIM + h * 64 + hi * 4;
#pragma unroll
    for (int db = 0; db < 2; db++) {
#pragma unroll
      for (int gq = 0; gq < 4; gq++) {
        int doff = db * 32 + gq * 8;
        float4 old = *(float4*)(tfp + doff);
        float4 nv;
        float a0 = (db ? ot1[gq * 4 + 0] : ot0[gq * 4 + 0]) * inv;
        float a1 = (db ? ot1[gq * 4 + 1] : ot0[gq * 4 + 1]) * inv;
        float a2 = (db ? ot1[gq * 4 + 2] : ot0[gq * 4 + 2]) * inv;
        float a3 = (db ? ot1[gq * 4 + 3] : ot0[gq * 4 + 3]) * inv;
        nv.x = old.x + a0; nv.y = old.y + a1; nv.z = old.z + a2; nv.w = old.w + a3;
        *(float4*)(tfp + doff) = nv;
        bf16x4 ob;
        ob[0] = (bf16_t)nv.x; ob[1] = (bf16_t)nv.y;
        ob[2] = (bf16_t)nv.z; ob[3] = (bf16_t)nv.w;
        *(bf16x4*)(tbp + doff) = ob;
      }
    }
  }
}

extern "C" void kernel_launch(void* const* d_in, const int* in_sizes, int n_in,
                              void* d_out, int out_size, void* d_ws, size_t ws_size,
                              hipStream_t stream) {
  (void)in_sizes; (void)n_in; (void)out_size; (void)ws_size;
  const float* x1 = (const float*)d_in[0];
  const float* x2 = (const float*)d_in[1];
  const float* Wq1 = (const float*)d_in[2];
  const float* bq1 = (const float*)d_in[3];
  const float* Wk1 = (const float*)d_in[4];
  const float* bk1 = (const float*)d_in[5];
  const float* Wv1 = (const float*)d_in[6];
  const float* bv1 = (const float*)d_in[7];
  const float* ln1_g = (const float*)d_in[8];
  const float* ln1_b = (const float*)d_in[9];
  const float* Wq2 = (const float*)d_in[10];
  const float* bq2 = (const float*)d_in[11];
  const float* Wk2 = (const float*)d_in[12];
  const float* bk2 = (const float*)d_in[13];
  const float* Wv2 = (const float*)d_in[14];
  const float* bv2 = (const float*)d_in[15];
  const float* ln2_g = (const float*)d_in[16];
  const float* ln2_b = (const float*)d_in[17];
  const float* out1_w = (const float*)d_in[18];
  const float* out1_b = (const float*)d_in[19];
  const float* bn1_g = (const float*)d_in[20];
  const float* bn1_b = (const float*)d_in[21];
  const float* out2_w = (const float*)d_in[22];
  const float* out2_b = (const float*)d_in[23];
  const float* bn2_g = (const float*)d_in[24];
  const float* bn2_b = (const float*)d_in[25];

  const size_t WMAT = 512 * 512;
  char* ws = (char*)d_ws;
  bf16_t* wb = (bf16_t*)ws;
  size_t off = 20 * WMAT * sizeof(bf16_t);
  float* t1f = (float*)(ws + off); off += (size_t)MROWS * CDIM * 4;
  float* t2f = (float*)(ws + off); off += (size_t)MROWS * CDIM * 4;
  bf16_t* t1b = (bf16_t*)(ws + off); off += (size_t)MROWS * CDIM * 2;
  bf16_t* t2b = (bf16_t*)(ws + off); off += (size_t)MROWS * CDIM * 2;
  bf16_t* l1b = (bf16_t*)(ws + off); off += (size_t)MROWS * CDIM * 2;
  bf16_t* l2b = (bf16_t*)(ws + off); off += (size_t)MROWS * CDIM * 2;
  bf16_t* q1b = (bf16_t*)(ws + off); off += (size_t)MROWS * CDIM * 2;
  bf16_t* k1b = (bf16_t*)(ws + off); off += (size_t)MROWS * CDIM * 2;
  bf16_t* v1b = (bf16_t*)(ws + off); off += (size_t)MROWS * CDIM * 2;  // V^T [b][512][1568]
  bf16_t* q2b = (bf16_t*)(ws + off); off += (size_t)MROWS * CDIM * 2;
  bf16_t* k2b = (bf16_t*)(ws + off); off += (size_t)MROWS * CDIM * 2;
  bf16_t* v2b = (bf16_t*)(ws + off); off += (size_t)MROWS * CDIM * 2;  // V^T

  CastArgs ca;
  for (int i = 0; i < 3; i++) {
    ca.s[0 + i] = Wq1 + (size_t)i * WMAT;
    ca.s[3 + i] = Wk1 + (size_t)i * WMAT;
    ca.s[6 + i] = Wv1 + (size_t)i * WMAT;
    ca.s[9 + i] = Wq2 + (size_t)i * WMAT;
    ca.s[12 + i] = Wk2 + (size_t)i * WMAT;
    ca.s[15 + i] = Wv2 + (size_t)i * WMAT;
  }
  ca.s[18] = out1_w;
  ca.s[19] = out2_w;
  cast_kernel<<<5120, 256, 0, stream>>>(ca, wb);

  TokArgs ta;
  ta.x[0] = x1; ta.x[1] = x2;
  ta.tf[0] = t1f; ta.tf[1] = t2f;
  ta.tb[0] = t1b; ta.tb[1] = t2b;
  tok_kernel<<<dim3(49, 16, 8), dim3(32, 8), 0, stream>>>(ta);

  AttnArgs aa;
  aa.q[0] = q1b; aa.q[1] = q2b;
  aa.k[0] = k1b; aa.k[1] = k2b;
  aa.v[0] = v1b; aa.v[1] = v2b;
  aa.tf[0] = t1f; aa.tf[1] = t2f;
  aa.tb[0] = t1b; aa.tb[1] = t2b;

  for (int i = 0; i < 3; i++) {
    ln_kernel<<<2 * MROWS, 64, 0, stream>>>(t1f, t2f,
        ln1_g + i * 512, ln1_b + i * 512, ln2_g + i * 512, ln2_b + i * 512,
        l1b, l2b);
    ProjArgs pa;
    pa.A0[0] = l1b; pa.W0[0] = wb + (0 + i) * WMAT; pa.b0[0] = bq1 + i * 512; pa.o0[0] = q1b;
    pa.A0[1] = t2b; pa.W0[1] = wb + (3 + i) * WMAT; pa.b0[1] = bk1 + i * 512; pa.o0[1] = k1b;
    pa.A0[2] = l2b; pa.W0[2] = wb + (9 + i) * WMAT; pa.b0[2] = bq2 + i * 512; pa.o0[2] = q2b;
    pa.A0[3] = t1b; pa.W0[3] = wb + (12 + i) * WMAT; pa.b0[3] = bk2 + i * 512; pa.o0[3] = k2b;
    pa.W2[0] = wb + (6 + i) * WMAT; pa.B2[0] = t2b; pa.b2[0] = bv1 + i * 512; pa.o2[0] = v1b;
    pa.W2[1] = wb + (15 + i) * WMAT; pa.B2[1] = t1b; pa.b2[1] = bv2 + i * 512; pa.o2[1] = v2b;
    proj_kernel<<<1200, 256, 0, stream>>>(pa);
    attn_kernel<<<832, 256, 0, stream>>>(aa);
  }

  float* out = (float*)d_out;
  head_kernel<<<dim3(13, 4, 8), 256, 0, stream>>>(
      wb + 18 * WMAT, wb + 19 * WMAT, t1b, t2b,
      out1_b, out2_b, bn1_g, bn1_b, bn2_g, bn2_b, out);
}